// Round 1
// baseline (705.035 us; speedup 1.0000x reference)
//
#include <hip/hip_runtime.h>
#include <hip/hip_bf16.h>

typedef __bf16 bf16;
typedef __bf16 bf16x8 __attribute__((ext_vector_type(8)));
typedef float f32x4 __attribute__((ext_vector_type(4)));

#define DD 2048

__device__ __forceinline__ void glds16(const void* g, void* l) {
  __builtin_amdgcn_global_load_lds((const __attribute__((address_space(1))) void*)g,
                                   (__attribute__((address_space(3))) void*)l, 16, 0, 0);
}

__device__ __forceinline__ f32x4 mfma16(bf16x8 a, bf16x8 b, f32x4 c) {
  return __builtin_amdgcn_mfma_f32_16x16x32_bf16(a, b, c, 0, 0, 0);
}

// ---------------- fp32 -> bf16 convert ----------------
__global__ __launch_bounds__(256) void cvt_bf16(const float* __restrict__ in, bf16* __restrict__ out) {
  size_t i = ((size_t)blockIdx.x * 256 + threadIdx.x) * 8;
  float4 a = *(const float4*)(in + i);
  float4 b = *(const float4*)(in + i + 4);
  bf16x8 o;
  o[0] = (bf16)a.x; o[1] = (bf16)a.y; o[2] = (bf16)a.z; o[3] = (bf16)a.w;
  o[4] = (bf16)b.x; o[5] = (bf16)b.y; o[6] = (bf16)b.z; o[7] = (bf16)b.w;
  *(bf16x8*)(out + i) = o;
}

// ---------------- RMSNorm (optionally with lambda-blend of x,x0), fp32 in -> bf16 out ----------------
template<bool BLEND>
__global__ __launch_bounds__(256) void prenorm_k(const float* __restrict__ x, const float* __restrict__ x0,
                                                 const float* __restrict__ lambdas, bf16* __restrict__ out) {
  const int t = blockIdx.x, tid = threadIdx.x;
  const float4* xr = (const float4*)(x + (size_t)t * DD);
  float4 a0 = xr[2 * tid], a1 = xr[2 * tid + 1];
  float v[8] = {a0.x, a0.y, a0.z, a0.w, a1.x, a1.y, a1.z, a1.w};
  if (BLEND) {
    const float l0 = lambdas[0], l1 = lambdas[1];
    const float4* yr = (const float4*)(x0 + (size_t)t * DD);
    float4 b0 = yr[2 * tid], b1 = yr[2 * tid + 1];
    float w[8] = {b0.x, b0.y, b0.z, b0.w, b1.x, b1.y, b1.z, b1.w};
#pragma unroll
    for (int i = 0; i < 8; ++i) v[i] = l0 * v[i] + l1 * w[i];
  }
  float ss = 0.f;
#pragma unroll
  for (int i = 0; i < 8; ++i) ss += v[i] * v[i];
#pragma unroll
  for (int off = 1; off < 64; off <<= 1) ss += __shfl_xor(ss, off, 64);
  __shared__ float red[4];
  const int wid = tid >> 6;
  if ((tid & 63) == 0) red[wid] = ss;
  __syncthreads();
  ss = red[0] + red[1] + red[2] + red[3];
  const float sc = rsqrtf(ss * (1.0f / DD) + 1.1920928955078125e-07f);
  bf16x8 o;
#pragma unroll
  for (int i = 0; i < 8; ++i) o[i] = (bf16)(v[i] * sc);
  *(bf16x8*)(out + (size_t)t * DD + tid * 8) = o;
}

// ---------------- per-(t,h) RMSNorm + rotary, in-place on bf16 q/k ----------------
__global__ __launch_bounds__(256) void rope_k(bf16* __restrict__ qg, bf16* __restrict__ kg) {
  const int tid = threadIdx.x, lane = tid & 63, wid = tid >> 6;
  const int p = blockIdx.x * 4 + wid;          // [arr(2)][t(2048)][h(16)]
  bf16* base = ((p >> 15) ? kg : qg);
  const int t = (p >> 4) & 2047, hh = p & 15;
  base += (size_t)t * DD + hh * 128;
  float x1 = (float)base[lane], x2 = (float)base[lane + 64];
  float ss = x1 * x1 + x2 * x2;
#pragma unroll
  for (int off = 1; off < 64; off <<= 1) ss += __shfl_xor(ss, off, 64);
  const float sc = rsqrtf(ss * (1.0f / 128.0f) + 1.1920928955078125e-07f);
  x1 *= sc; x2 *= sc;
  // inv_freq = 10000^(-lane/64) = exp2(-lane/64 * log2(10000))
  const float fr = (float)t * exp2f((float)lane * (-13.287712379549449f / 64.0f));
  const float s = sinf(fr), c = cosf(fr);
  base[lane]      = (bf16)(x1 * c + x2 * s);
  base[lane + 64] = (bf16)(-x1 * s + x2 * c);
}

// ---------------- GEMM core: C = A[M,K] * B[N,K]^T, 128x128 tile, BK=64, 4 waves ----------------
// LDS layout: row-major [128][64] bf16 (128B rows), 16B slots XOR-swizzled by (row&7).
// Staged with global_load_lds (linear dest) + inverse-swizzled global source (rule 21).
__device__ __forceinline__ void gemm_core(const bf16* __restrict__ A, const bf16* __restrict__ B,
                                          int K, int row0, int col0, bf16* As, bf16* Bs,
                                          f32x4 acc[4][4]) {
  const int tid = threadIdx.x;
  const int lane = tid & 63, wid = tid >> 6;
  const int wr = (wid >> 1) * 64, wc = (wid & 1) * 64;
  const int l15 = lane & 15, g = lane >> 4;
  for (int k0 = 0; k0 < K; k0 += 64) {
    __syncthreads();               // previous iteration's readers done
#pragma unroll
    for (int r = 0; r < 4; ++r) {
      int e = tid + r * 256;       // e in [0,1024): row=e>>3 (0..127), slot=e&7
      int row = e >> 3, slot = e & 7;
      int cs = (slot ^ (row & 7)) * 8;  // pre-swizzled source chunk
      glds16(A + (size_t)(row0 + row) * K + k0 + cs, As + e * 8);
      glds16(B + (size_t)(col0 + row) * K + k0 + cs, Bs + e * 8);
    }
    __syncthreads();
#pragma unroll
    for (int ks = 0; ks < 2; ++ks) {
      bf16x8 af[4], bfr[4];
#pragma unroll
      for (int m = 0; m < 4; ++m) {
        int row = wr + m * 16 + l15;
        af[m] = *(const bf16x8*)(As + row * 64 + (((ks * 4 + g) ^ (row & 7)) * 8));
      }
#pragma unroll
      for (int n = 0; n < 4; ++n) {
        int row = wc + n * 16 + l15;
        bfr[n] = *(const bf16x8*)(Bs + row * 64 + (((ks * 4 + g) ^ (row & 7)) * 8));
      }
#pragma unroll
      for (int m = 0; m < 4; ++m)
#pragma unroll
        for (int n = 0; n < 4; ++n)
          acc[m][n] = mfma16(af[m], bfr[n], acc[m][n]);
    }
  }
}

// D layout (16x16x32): col=lane&15 (N side), row=(lane>>4)*4+j (M side)  [m89-verified]
#define GEMM_EPI(STMT)                                                        \
  { const int lane_ = threadIdx.x & 63, wid_ = threadIdx.x >> 6;              \
    const int l15_ = lane_ & 15, g_ = lane_ >> 4;                             \
    const int wr_ = (wid_ >> 1) * 64, wc_ = (wid_ & 1) * 64;                  \
    _Pragma("unroll") for (int m = 0; m < 4; ++m)                             \
    _Pragma("unroll") for (int n = 0; n < 4; ++n)                             \
    _Pragma("unroll") for (int j = 0; j < 4; ++j) {                           \
      int grow = row0 + wr_ + m * 16 + g_ * 4 + j;                            \
      int gcol = col0 + wc_ + n * 16 + l15_;                                  \
      float vacc = acc[m][n][j];                                              \
      STMT; } }

// QKV: one launch, blockIdx.z selects weight/output; z==2 fuses the value-embedding blend.
__global__ __launch_bounds__(256) void gemm_qkv(const bf16* __restrict__ A,
    const bf16* __restrict__ Wq, const bf16* __restrict__ Wk, const bf16* __restrict__ Wv,
    bf16* __restrict__ oq, bf16* __restrict__ ok, bf16* __restrict__ ov,
    const float* __restrict__ vi, const float* __restrict__ lambp) {
  __shared__ alignas(16) bf16 As[8192];
  __shared__ alignas(16) bf16 Bs[8192];
  const int z = blockIdx.z;
  const bf16* B = (z == 0) ? Wq : (z == 1) ? Wk : Wv;
  bf16* out = (z == 0) ? oq : (z == 1) ? ok : ov;
  const int row0 = blockIdx.y * 128, col0 = blockIdx.x * 128;
  f32x4 acc[4][4] = {};
  gemm_core(A, B, DD, row0, col0, As, Bs, acc);
  if (z < 2) {
    GEMM_EPI( out[(size_t)grow * DD + gcol] = (bf16)vacc; )
  } else {
    const float lam = *lambp;
    GEMM_EPI( out[(size_t)grow * DD + gcol] =
                (bf16)((1.0f - lam) * vacc + lam * vi[(size_t)grow * DD + gcol]); )
  }
}

// EPI: 2 = f32 store (wo), 3 = relu^2 -> bf16 (fc), 4 = aux + acc -> f32 (proj+residual)
template<int EPI>
__global__ __launch_bounds__(256) void gemm_ep(const bf16* __restrict__ A, const bf16* __restrict__ B,
                                               void* __restrict__ outv, const float* __restrict__ aux,
                                               int N, int K) {
  __shared__ alignas(16) bf16 As[8192];
  __shared__ alignas(16) bf16 Bs[8192];
  const int row0 = blockIdx.y * 128, col0 = blockIdx.x * 128;
  f32x4 acc[4][4] = {};
  gemm_core(A, B, K, row0, col0, As, Bs, acc);
  if (EPI == 2) { float* out = (float*)outv;
    GEMM_EPI( out[(size_t)grow * N + gcol] = vacc; ) }
  if (EPI == 3) { bf16* out = (bf16*)outv;
    GEMM_EPI( float r = fmaxf(vacc, 0.f); out[(size_t)grow * N + gcol] = (bf16)(r * r); ) }
  if (EPI == 4) { float* out = (float*)outv;
    GEMM_EPI( out[(size_t)grow * N + gcol] = aux[(size_t)grow * N + gcol] + vacc; ) }
}

// ---------------- causal flash attention ----------------
// grid (32 q-blocks, 16 heads), 4 waves/block, each wave owns 16 q-rows, KB=32 K/V tiles.
__global__ __launch_bounds__(256) void attn_k(const bf16* __restrict__ qg, const bf16* __restrict__ kg,
                                              const bf16* __restrict__ vg, bf16* __restrict__ yg) {
  __shared__ alignas(16) bf16 Ks[32 * 128];   // [k][d], 16B slots swizzled by k&7
  __shared__ alignas(16) bf16 Vt[128 * 32];   // [d][k], 16B slots swizzled by d&3
  __shared__ alignas(16) bf16 Pl[4][16 * 32]; // per-wave P [q][k]
  const int h = blockIdx.y, qb = blockIdx.x;
  const int tid = threadIdx.x, lane = tid & 63, wid = tid >> 6;
  const int l15 = lane & 15, g = lane >> 4;
  const int qrow = qb * 64 + wid * 16;
  const float scale = 0.08838834764831845f;   // 1/sqrt(128)
  bf16x8 aQ[4];
  {
    const bf16* qp = qg + (size_t)(qrow + l15) * DD + h * 128 + g * 8;
#pragma unroll
    for (int kc = 0; kc < 4; ++kc) aQ[kc] = *(const bf16x8*)(qp + kc * 32);
  }
  f32x4 acc[8] = {};
  f32x4 m4, l4 = {0.f, 0.f, 0.f, 0.f};
  m4[0] = m4[1] = m4[2] = m4[3] = -INFINITY;
  const int nkt = qb * 2 + 2;
  for (int kt = 0; kt < nkt; ++kt) {
    const int kbase = kt * 32;
    bf16x8 vv[2];
#pragma unroll
    for (int c = 0; c < 2; ++c) {
      int e = tid + c * 256;
      int kk = e >> 4, d0 = (e & 15) * 8;
      vv[c] = *(const bf16x8*)(vg + (size_t)(kbase + kk) * DD + h * 128 + d0);
    }
    __syncthreads();
#pragma unroll
    for (int r = 0; r < 2; ++r) {
      int e = tid + r * 256;           // row=e>>4 (0..31), slot=e&15
      int row = e >> 4, slot = e & 15;
      int cs = (slot ^ (row & 7)) * 8;
      glds16(kg + (size_t)(kbase + row) * DD + h * 128 + cs, Ks + e * 8);
    }
#pragma unroll
    for (int c = 0; c < 2; ++c) {
      int e = tid + c * 256;
      int kk = e >> 4, d0 = (e & 15) * 8;
#pragma unroll
      for (int i = 0; i < 8; ++i) {
        int d = d0 + i;
        Vt[d * 32 + (((kk >> 3) ^ (d & 3)) * 8) + (kk & 7)] = vv[c][i];
      }
    }
    __syncthreads();
    // S = Q * K^T  (rows q=4g+j, cols k=l15 / 16+l15)
    f32x4 S0 = {}, S1 = {};
#pragma unroll
    for (int kc = 0; kc < 4; ++kc) {
      int r0 = l15, r1 = 16 + l15;
      bf16x8 b0 = *(const bf16x8*)(Ks + r0 * 128 + (((kc * 4 + g) ^ (r0 & 7)) * 8));
      bf16x8 b1 = *(const bf16x8*)(Ks + r1 * 128 + (((kc * 4 + g) ^ (r1 & 7)) * 8));
      S0 = mfma16(aQ[kc], b0, S0);
      S1 = mfma16(aQ[kc], b1, S1);
    }
    const int k0i = kbase + l15, k1i = k0i + 16;
    f32x4 p0, p1, rm;
#pragma unroll
    for (int j = 0; j < 4; ++j) {
      int q = qrow + g * 4 + j;
      float s0 = (k0i <= q) ? S0[j] * scale : -INFINITY;
      float s1 = (k1i <= q) ? S1[j] * scale : -INFINITY;
      p0[j] = s0; p1[j] = s1;
      rm[j] = fmaxf(s0, s1);
    }
#pragma unroll
    for (int off = 1; off < 16; off <<= 1)
#pragma unroll
      for (int j = 0; j < 4; ++j) rm[j] = fmaxf(rm[j], __shfl_xor(rm[j], off, 64));
    f32x4 rf, rs;
#pragma unroll
    for (int j = 0; j < 4; ++j) {
      float mn = fmaxf(m4[j], rm[j]);
      rf[j] = __expf(m4[j] - mn);
      float e0 = __expf(p0[j] - mn);
      float e1 = __expf(p1[j] - mn);
      p0[j] = e0; p1[j] = e1;
      rs[j] = e0 + e1;
      m4[j] = mn;
    }
#pragma unroll
    for (int off = 1; off < 16; off <<= 1)
#pragma unroll
      for (int j = 0; j < 4; ++j) rs[j] += __shfl_xor(rs[j], off, 64);
#pragma unroll
    for (int j = 0; j < 4; ++j) l4[j] = l4[j] * rf[j] + rs[j];
#pragma unroll
    for (int dt = 0; dt < 8; ++dt)
#pragma unroll
      for (int j = 0; j < 4; ++j) acc[dt][j] *= rf[j];
    // P to per-wave LDS [q][k]
#pragma unroll
    for (int j = 0; j < 4; ++j) {
      Pl[wid][(g * 4 + j) * 32 + l15]      = (bf16)p0[j];
      Pl[wid][(g * 4 + j) * 32 + 16 + l15] = (bf16)p1[j];
    }
    bf16x8 aP = *(const bf16x8*)(&Pl[wid][l15 * 32 + g * 8]);
#pragma unroll
    for (int dt = 0; dt < 8; ++dt) {
      int d = dt * 16 + l15;
      bf16x8 bV = *(const bf16x8*)(Vt + d * 32 + ((g ^ (d & 3)) * 8));
      acc[dt] = mfma16(aP, bV, acc[dt]);
    }
  }
#pragma unroll
  for (int dt = 0; dt < 8; ++dt)
#pragma unroll
    for (int j = 0; j < 4; ++j) {
      int q = qrow + g * 4 + j;
      yg[(size_t)q * DD + h * 128 + dt * 16 + l15] = (bf16)(acc[dt][j] / l4[j]);
    }
}

extern "C" void kernel_launch(void* const* d_in, const int* in_sizes, int n_in,
                              void* d_out, int out_size, void* d_ws, size_t ws_size,
                              hipStream_t stream) {
  const float* x       = (const float*)d_in[0];
  const float* vi      = (const float*)d_in[1];
  const float* x0      = (const float*)d_in[2];
  const float* wq      = (const float*)d_in[3];
  const float* wk      = (const float*)d_in[4];
  const float* wv      = (const float*)d_in[5];
  const float* wo      = (const float*)d_in[6];
  const float* lamb    = (const float*)d_in[7];
  const float* lambdas = (const float*)d_in[8];
  const float* wfc     = (const float*)d_in[9];
  const float* wproj   = (const float*)d_in[10];
  float* out = (float*)d_out;

  char* wsb = (char*)d_ws;
  size_t off = 0;
  auto alloc = [&](size_t bytes) { void* p = wsb + off; off = (off + bytes + 255) & ~(size_t)255; return p; };
  const size_t DD2 = (size_t)DD * DD;
  bf16* wq_b  = (bf16*)alloc(DD2 * 2);
  bf16* wk_b  = (bf16*)alloc(DD2 * 2);
  bf16* wv_b  = (bf16*)alloc(DD2 * 2);
  bf16* wo_b  = (bf16*)alloc(DD2 * 2);
  bf16* wfc_b = (bf16*)alloc(DD2 * 8);
  bf16* wpj_b = (bf16*)alloc(DD2 * 8);
  bf16* xn_b  = (bf16*)alloc(DD2 * 2);
  bf16* q_b   = (bf16*)alloc(DD2 * 2);
  bf16* k_b   = (bf16*)alloc(DD2 * 2);
  bf16* v_b   = (bf16*)alloc(DD2 * 2);
  bf16* y_b   = (bf16*)alloc(DD2 * 2);
  float* a_f  = (float*)alloc(DD2 * 4);
  bf16* an_b  = (bf16*)alloc(DD2 * 2);
  bf16* h_b   = (bf16*)alloc(DD2 * 8);

  cvt_bf16<<<2048, 256, 0, stream>>>(wq, wq_b);
  cvt_bf16<<<2048, 256, 0, stream>>>(wk, wk_b);
  cvt_bf16<<<2048, 256, 0, stream>>>(wv, wv_b);
  cvt_bf16<<<2048, 256, 0, stream>>>(wo, wo_b);
  cvt_bf16<<<8192, 256, 0, stream>>>(wfc, wfc_b);
  cvt_bf16<<<8192, 256, 0, stream>>>(wproj, wpj_b);

  prenorm_k<true><<<2048, 256, 0, stream>>>(x, x0, lambdas, xn_b);
  gemm_qkv<<<dim3(16, 16, 3), 256, 0, stream>>>(xn_b, wq_b, wk_b, wv_b, q_b, k_b, v_b, vi, lamb);
  rope_k<<<16384, 256, 0, stream>>>(q_b, k_b);
  attn_k<<<dim3(32, 16), 256, 0, stream>>>(q_b, k_b, v_b, y_b);
  gemm_ep<2><<<dim3(16, 16), 256, 0, stream>>>(y_b, wo_b, (void*)a_f, nullptr, DD, DD);
  prenorm_k<false><<<2048, 256, 0, stream>>>(a_f, nullptr, nullptr, an_b);
  gemm_ep<3><<<dim3(64, 16), 256, 0, stream>>>(an_b, wfc_b, (void*)h_b, nullptr, 4 * DD, DD);
  gemm_ep<4><<<dim3(16, 16), 256, 0, stream>>>(h_b, wpj_b, (void*)out, a_f, DD, 4 * DD);
}

// Round 2
// 496.448 us; speedup vs baseline: 1.4202x; 1.4202x over previous
//
#include <hip/hip_runtime.h>
#include <hip/hip_bf16.h>

typedef __bf16 bf16;
typedef __bf16 bf16x8 __attribute__((ext_vector_type(8)));
typedef float f32x4 __attribute__((ext_vector_type(4)));

#define DD 2048
#define DD2 4194304ull

__device__ __forceinline__ void glds16(const void* g, void* l) {
  __builtin_amdgcn_global_load_lds((const __attribute__((address_space(1))) void*)g,
                                   (__attribute__((address_space(3))) void*)l, 16, 0, 0);
}

__device__ __forceinline__ f32x4 mfma16(bf16x8 a, bf16x8 b, f32x4 c) {
  return __builtin_amdgcn_mfma_f32_16x16x32_bf16(a, b, c, 0, 0, 0);
}

// ---------------- fp32 -> bf16 convert ----------------
__global__ __launch_bounds__(256) void cvt_bf16(const float* __restrict__ in, bf16* __restrict__ out) {
  size_t i = ((size_t)blockIdx.x * 256 + threadIdx.x) * 8;
  float4 a = *(const float4*)(in + i);
  float4 b = *(const float4*)(in + i + 4);
  bf16x8 o;
  o[0] = (bf16)a.x; o[1] = (bf16)a.y; o[2] = (bf16)a.z; o[3] = (bf16)a.w;
  o[4] = (bf16)b.x; o[5] = (bf16)b.y; o[6] = (bf16)b.z; o[7] = (bf16)b.w;
  *(bf16x8*)(out + i) = o;
}

// ---------------- RMSNorm (optionally with lambda-blend of x,x0), fp32 in -> bf16 out ----------------
template<bool BLEND>
__global__ __launch_bounds__(256) void prenorm_k(const float* __restrict__ x, const float* __restrict__ x0,
                                                 const float* __restrict__ lambdas, bf16* __restrict__ out) {
  const int t = blockIdx.x, tid = threadIdx.x;
  const float4* xr = (const float4*)(x + (size_t)t * DD);
  float4 a0 = xr[2 * tid], a1 = xr[2 * tid + 1];
  float v[8] = {a0.x, a0.y, a0.z, a0.w, a1.x, a1.y, a1.z, a1.w};
  if (BLEND) {
    const float l0 = lambdas[0], l1 = lambdas[1];
    const float4* yr = (const float4*)(x0 + (size_t)t * DD);
    float4 b0 = yr[2 * tid], b1 = yr[2 * tid + 1];
    float w[8] = {b0.x, b0.y, b0.z, b0.w, b1.x, b1.y, b1.z, b1.w};
#pragma unroll
    for (int i = 0; i < 8; ++i) v[i] = l0 * v[i] + l1 * w[i];
  }
  float ss = 0.f;
#pragma unroll
  for (int i = 0; i < 8; ++i) ss += v[i] * v[i];
#pragma unroll
  for (int off = 1; off < 64; off <<= 1) ss += __shfl_xor(ss, off, 64);
  __shared__ float red[4];
  const int wid = tid >> 6;
  if ((tid & 63) == 0) red[wid] = ss;
  __syncthreads();
  ss = red[0] + red[1] + red[2] + red[3];
  const float sc = rsqrtf(ss * (1.0f / DD) + 1.1920928955078125e-07f);
  bf16x8 o;
#pragma unroll
  for (int i = 0; i < 8; ++i) o[i] = (bf16)(v[i] * sc);
  *(bf16x8*)(out + (size_t)t * DD + tid * 8) = o;
}

// ---------------- per-(t,h) RMSNorm + rotary, in-place on bf16 q/k ----------------
__global__ __launch_bounds__(256) void rope_k(bf16* __restrict__ qg, bf16* __restrict__ kg) {
  const int tid = threadIdx.x, lane = tid & 63, wid = tid >> 6;
  const int p = blockIdx.x * 4 + wid;          // [arr(2)][t(2048)][h(16)]
  bf16* base = ((p >> 15) ? kg : qg);
  const int t = (p >> 4) & 2047, hh = p & 15;
  base += (size_t)t * DD + hh * 128;
  float x1 = (float)base[lane], x2 = (float)base[lane + 64];
  float ss = x1 * x1 + x2 * x2;
#pragma unroll
  for (int off = 1; off < 64; off <<= 1) ss += __shfl_xor(ss, off, 64);
  const float sc = rsqrtf(ss * (1.0f / 128.0f) + 1.1920928955078125e-07f);
  x1 *= sc; x2 *= sc;
  const float fr = (float)t * exp2f((float)lane * (-13.287712379549449f / 64.0f));
  const float s = sinf(fr), c = cosf(fr);
  base[lane]      = (bf16)(x1 * c + x2 * s);
  base[lane + 64] = (bf16)(-x1 * s + x2 * c);
}

// ---------------- V transpose: v[t][2048] -> vt[d2][t]  (d2 = h*128+d) ----------------
__global__ __launch_bounds__(256) void vt_k(const bf16* __restrict__ v, bf16* __restrict__ vt) {
  __shared__ alignas(16) bf16 tile[16 * 128];
  const int tb = blockIdx.x, hb = blockIdx.y, tid = threadIdx.x;
  glds16(v + (size_t)(tb * 16 + (tid >> 4)) * DD + hb * 128 + (tid & 15) * 8, tile + tid * 8);
  __syncthreads();
  const int d_l = tid & 127, tc = tid >> 7;
  bf16x8 o;
#pragma unroll
  for (int i = 0; i < 8; ++i) o[i] = tile[(tc * 8 + i) * 128 + d_l];
  *(bf16x8*)(vt + (size_t)(hb * 128 + d_l) * DD + tb * 16 + tc * 8) = o;
}

// ---------------- GEMM core: C = A[M,Kstride] * B[N,Kstride]^T over Klen, 128x128 tile ----------------
__device__ __forceinline__ void gemm_core(const bf16* __restrict__ A, const bf16* __restrict__ B,
                                          int Kstride, int Klen, int row0, int col0, bf16* As, bf16* Bs,
                                          f32x4 acc[4][4]) {
  const int tid = threadIdx.x;
  const int lane = tid & 63, wid = tid >> 6;
  const int wr = (wid >> 1) * 64, wc = (wid & 1) * 64;
  const int l15 = lane & 15, g = lane >> 4;
  for (int k0 = 0; k0 < Klen; k0 += 64) {
    __syncthreads();
#pragma unroll
    for (int r = 0; r < 4; ++r) {
      int e = tid + r * 256;
      int row = e >> 3, slot = e & 7;
      int cs = (slot ^ (row & 7)) * 8;
      glds16(A + (size_t)(row0 + row) * Kstride + k0 + cs, As + e * 8);
      glds16(B + (size_t)(col0 + row) * Kstride + k0 + cs, Bs + e * 8);
    }
    __syncthreads();
#pragma unroll
    for (int ks = 0; ks < 2; ++ks) {
      bf16x8 af[4], bfr[4];
#pragma unroll
      for (int m = 0; m < 4; ++m) {
        int row = wr + m * 16 + l15;
        af[m] = *(const bf16x8*)(As + row * 64 + (((ks * 4 + g) ^ (row & 7)) * 8));
      }
#pragma unroll
      for (int n = 0; n < 4; ++n) {
        int row = wc + n * 16 + l15;
        bfr[n] = *(const bf16x8*)(Bs + row * 64 + (((ks * 4 + g) ^ (row & 7)) * 8));
      }
#pragma unroll
      for (int m = 0; m < 4; ++m)
#pragma unroll
        for (int n = 0; n < 4; ++n)
          acc[m][n] = mfma16(af[m], bfr[n], acc[m][n]);
    }
  }
}

#define GEMM_EPI(STMT)                                                        \
  { const int lane_ = threadIdx.x & 63, wid_ = threadIdx.x >> 6;              \
    const int l15_ = lane_ & 15, g_ = lane_ >> 4;                             \
    const int wr_ = (wid_ >> 1) * 64, wc_ = (wid_ & 1) * 64;                  \
    _Pragma("unroll") for (int m = 0; m < 4; ++m)                             \
    _Pragma("unroll") for (int n = 0; n < 4; ++n)                             \
    _Pragma("unroll") for (int j = 0; j < 4; ++j) {                           \
      int grow = row0 + wr_ + m * 16 + g_ * 4 + j;                            \
      int gcol = col0 + wc_ + n * 16 + l15_;                                  \
      float vacc = acc[m][n][j];                                              \
      STMT; } }

__global__ __launch_bounds__(256) void gemm_qkv(const bf16* __restrict__ A,
    const bf16* __restrict__ Wq, const bf16* __restrict__ Wk, const bf16* __restrict__ Wv,
    bf16* __restrict__ oq, bf16* __restrict__ ok, bf16* __restrict__ ov,
    const float* __restrict__ vi, const float* __restrict__ lambp) {
  __shared__ alignas(16) bf16 As[8192];
  __shared__ alignas(16) bf16 Bs[8192];
  const int z = blockIdx.z;
  const bf16* B = (z == 0) ? Wq : (z == 1) ? Wk : Wv;
  bf16* out = (z == 0) ? oq : (z == 1) ? ok : ov;
  const int row0 = blockIdx.y * 128, col0 = blockIdx.x * 128;
  f32x4 acc[4][4] = {};
  gemm_core(A, B, DD, DD, row0, col0, As, Bs, acc);
  if (z < 2) {
    GEMM_EPI( out[(size_t)grow * DD + gcol] = (bf16)vacc; )
  } else {
    const float lam = *lambp;
    GEMM_EPI( out[(size_t)grow * DD + gcol] =
                (bf16)((1.0f - lam) * vacc + lam * vi[(size_t)grow * DD + gcol]); )
  }
}

// EPI: 2 = f32 partial store (split-K via blockIdx.z), 3 = relu^2 -> bf16
template<int EPI>
__global__ __launch_bounds__(256) void gemm_ep(const bf16* __restrict__ A, const bf16* __restrict__ B,
                                               void* __restrict__ outv, int N, int Kstride, int Klen) {
  __shared__ alignas(16) bf16 As[8192];
  __shared__ alignas(16) bf16 Bs[8192];
  const int row0 = blockIdx.y * 128, col0 = blockIdx.x * 128;
  const int kofs = blockIdx.z * Klen;
  f32x4 acc[4][4] = {};
  gemm_core(A + kofs, B + kofs, Kstride, Klen, row0, col0, As, Bs, acc);
  if (EPI == 2) { float* out = (float*)outv + (size_t)blockIdx.z * DD2;
    GEMM_EPI( out[(size_t)grow * N + gcol] = vacc; ) }
  if (EPI == 3) { bf16* out = (bf16*)outv;
    GEMM_EPI( float r = fmaxf(vacc, 0.f); out[(size_t)grow * N + gcol] = (bf16)(r * r); ) }
}

// ---------------- split-K reduces ----------------
__global__ __launch_bounds__(256) void wo_red_prenorm(const float* __restrict__ p, float* __restrict__ a_f,
                                                      bf16* __restrict__ an) {
  const int t = blockIdx.x, tid = threadIdx.x;
  const size_t base = (size_t)t * DD + tid * 8;
  float4 a0 = *(const float4*)(p + base),        a1 = *(const float4*)(p + base + 4);
  float4 b0 = *(const float4*)(p + DD2 + base),  b1 = *(const float4*)(p + DD2 + base + 4);
  float v[8] = {a0.x + b0.x, a0.y + b0.y, a0.z + b0.z, a0.w + b0.w,
                a1.x + b1.x, a1.y + b1.y, a1.z + b1.z, a1.w + b1.w};
  *(float4*)(a_f + base)     = make_float4(v[0], v[1], v[2], v[3]);
  *(float4*)(a_f + base + 4) = make_float4(v[4], v[5], v[6], v[7]);
  float ss = 0.f;
#pragma unroll
  for (int i = 0; i < 8; ++i) ss += v[i] * v[i];
#pragma unroll
  for (int off = 1; off < 64; off <<= 1) ss += __shfl_xor(ss, off, 64);
  __shared__ float red[4];
  if ((tid & 63) == 0) red[tid >> 6] = ss;
  __syncthreads();
  ss = red[0] + red[1] + red[2] + red[3];
  const float sc = rsqrtf(ss * (1.0f / DD) + 1.1920928955078125e-07f);
  bf16x8 o;
#pragma unroll
  for (int i = 0; i < 8; ++i) o[i] = (bf16)(v[i] * sc);
  *(bf16x8*)(an + base) = o;
}

__global__ __launch_bounds__(256) void proj_red(const float* __restrict__ p, const float* __restrict__ a_f,
                                                float* __restrict__ out) {
  const size_t base = ((size_t)blockIdx.x * 256 + threadIdx.x) * 8;
#pragma unroll
  for (int h = 0; h < 2; ++h) {
    size_t i = base + h * 4;
    float4 r = *(const float4*)(a_f + i);
    float4 u = *(const float4*)(p + i);
    float4 w = *(const float4*)(p + DD2 + i);
    *(float4*)(out + i) = make_float4(r.x + u.x + w.x, r.y + u.y + w.y,
                                      r.z + u.z + w.z, r.w + u.w + w.w);
  }
}

// ---------------- causal flash attention, no-max softmax ----------------
// grid (32 qb, 16 h), qb reversed (heavy first). 4 waves, 16 q-rows each, KB=32 tiles.
__global__ __launch_bounds__(256) void attn_k(const bf16* __restrict__ qg, const bf16* __restrict__ kg,
                                              const bf16* __restrict__ vtg, bf16* __restrict__ yg) {
  __shared__ alignas(16) bf16 Ks[32 * 128];   // [k][d], 16B slots swizzled by k&7
  __shared__ alignas(16) bf16 Vt[128 * 32];   // [d][k], 16B slots swizzled by d&3
  __shared__ alignas(16) bf16 Pl[4][16 * 32]; // per-wave P [q][k], chunk swizzled by q>>2
  const int h = blockIdx.y, qb = 31 - blockIdx.x;
  const int tid = threadIdx.x, lane = tid & 63, wid = tid >> 6;
  const int l15 = lane & 15, g = lane >> 4;
  const int qrow = qb * 64 + wid * 16;
  const float scale = 0.08838834764831845f;   // 1/sqrt(128)
  bf16x8 aQ[4];
  {
    const bf16* qp = qg + (size_t)(qrow + l15) * DD + h * 128 + g * 8;
#pragma unroll
    for (int kc = 0; kc < 4; ++kc) aQ[kc] = *(const bf16x8*)(qp + kc * 32);
  }
  f32x4 acc[8] = {};
  f32x4 l4 = {0.f, 0.f, 0.f, 0.f};
  const int nkt = qb * 2 + 2;
  for (int kt = 0; kt < nkt; ++kt) {
    const int kbase = kt * 32;
    __syncthreads();
#pragma unroll
    for (int r = 0; r < 2; ++r) {
      int e = tid + r * 256;           // K: row=e>>4, slot=e&15
      int row = e >> 4, slot = e & 15;
      glds16(kg + (size_t)(kbase + row) * DD + h * 128 + ((slot ^ (row & 7)) * 8), Ks + e * 8);
    }
#pragma unroll
    for (int r = 0; r < 2; ++r) {
      int e = tid + r * 256;           // Vt: row d=e>>2, slot=e&3
      int d = e >> 2, slot = e & 3;
      glds16(vtg + (size_t)(h * 128 + d) * DD + kbase + ((slot ^ (d & 3)) * 8), Vt + e * 8);
    }
    __syncthreads();
    // S = Q * K^T  (rows q=4g+j, cols k=l15 / 16+l15)
    f32x4 S0 = {}, S1 = {};
#pragma unroll
    for (int kc = 0; kc < 4; ++kc) {
      int r0 = l15, r1 = 16 + l15;
      bf16x8 b0 = *(const bf16x8*)(Ks + r0 * 128 + (((kc * 4 + g) ^ (r0 & 7)) * 8));
      bf16x8 b1 = *(const bf16x8*)(Ks + r1 * 128 + (((kc * 4 + g) ^ (r1 & 7)) * 8));
      S0 = mfma16(aQ[kc], b0, S0);
      S1 = mfma16(aQ[kc], b1, S1);
    }
    const int k0i = kbase + l15, k1i = k0i + 16;
    // p = exp(s) — |s| <= 11.32 since q,k are RMS-normed, so no max-subtraction needed
    f32x4 p0, p1;
#pragma unroll
    for (int j = 0; j < 4; ++j) {
      int q = qrow + g * 4 + j;
      p0[j] = (k0i <= q) ? __expf(S0[j] * scale) : 0.f;
      p1[j] = (k1i <= q) ? __expf(S1[j] * scale) : 0.f;
      l4[j] += p0[j] + p1[j];
    }
    // P to per-wave LDS [q][k], chunk-swizzled by q>>2 (= writer's g)
    const int c0 = (l15 >> 3) ^ g, c1 = (2 + (l15 >> 3)) ^ g, w7 = l15 & 7;
#pragma unroll
    for (int j = 0; j < 4; ++j) {
      Pl[wid][(g * 4 + j) * 32 + c0 * 8 + w7] = (bf16)p0[j];
      Pl[wid][(g * 4 + j) * 32 + c1 * 8 + w7] = (bf16)p1[j];
    }
    bf16x8 aP = *(const bf16x8*)(&Pl[wid][l15 * 32 + ((g ^ (l15 >> 2)) * 8)]);
#pragma unroll
    for (int dt = 0; dt < 8; ++dt) {
      int d = dt * 16 + l15;
      bf16x8 bV = *(const bf16x8*)(Vt + d * 32 + ((g ^ (d & 3)) * 8));
      acc[dt] = mfma16(aP, bV, acc[dt]);
    }
  }
  // one final l-reduction over the 16 lanes sharing each q-row (xor flips l15 bits only)
#pragma unroll
  for (int off = 1; off < 16; off <<= 1)
#pragma unroll
    for (int j = 0; j < 4; ++j) l4[j] += __shfl_xor(l4[j], off, 64);
#pragma unroll
  for (int dt = 0; dt < 8; ++dt)
#pragma unroll
    for (int j = 0; j < 4; ++j) {
      int q = qrow + g * 4 + j;
      yg[(size_t)q * DD + h * 128 + dt * 16 + l15] = (bf16)(acc[dt][j] / l4[j]);
    }
}

extern "C" void kernel_launch(void* const* d_in, const int* in_sizes, int n_in,
                              void* d_out, int out_size, void* d_ws, size_t ws_size,
                              hipStream_t stream) {
  const float* x       = (const float*)d_in[0];
  const float* vi      = (const float*)d_in[1];
  const float* x0      = (const float*)d_in[2];
  const float* wq      = (const float*)d_in[3];
  const float* wk      = (const float*)d_in[4];
  const float* wv      = (const float*)d_in[5];
  const float* wo      = (const float*)d_in[6];
  const float* lamb    = (const float*)d_in[7];
  const float* lambdas = (const float*)d_in[8];
  const float* wfc     = (const float*)d_in[9];
  const float* wproj   = (const float*)d_in[10];
  float* out = (float*)d_out;

  char* wsb = (char*)d_ws;
  size_t off = 0;
  auto alloc = [&](size_t bytes) { void* p = wsb + off; off = (off + bytes + 255) & ~(size_t)255; return p; };
  bf16* wq_b  = (bf16*)alloc(DD2 * 2);
  bf16* wk_b  = (bf16*)alloc(DD2 * 2);
  bf16* wv_b  = (bf16*)alloc(DD2 * 2);
  bf16* wo_b  = (bf16*)alloc(DD2 * 2);
  bf16* wfc_b = (bf16*)alloc(DD2 * 8);
  bf16* wpj_b = (bf16*)alloc(DD2 * 8);
  // R1 region: xn/q/k/v (live through attn) later reused as 2x f32 split-K partials
  bf16* xn_b  = (bf16*)alloc(DD2 * 2);
  bf16* q_b   = (bf16*)alloc(DD2 * 2);
  bf16* k_b   = (bf16*)alloc(DD2 * 2);
  bf16* v_b   = (bf16*)alloc(DD2 * 2);
  float* part = (float*)xn_b;            // alias: 2 x DD2 f32 = exactly xn..v
  bf16* y_b   = (bf16*)alloc(DD2 * 2);
  float* a_f  = (float*)alloc(DD2 * 4);
  bf16* an_b  = (bf16*)alloc(DD2 * 2);
  bf16* h_b   = (bf16*)alloc(DD2 * 8);
  bf16* vt_b  = h_b;                     // alias: vt dead before fc writes h

  cvt_bf16<<<2048, 256, 0, stream>>>(wq, wq_b);
  cvt_bf16<<<2048, 256, 0, stream>>>(wk, wk_b);
  cvt_bf16<<<2048, 256, 0, stream>>>(wv, wv_b);
  cvt_bf16<<<2048, 256, 0, stream>>>(wo, wo_b);
  cvt_bf16<<<8192, 256, 0, stream>>>(wfc, wfc_b);
  cvt_bf16<<<8192, 256, 0, stream>>>(wproj, wpj_b);

  prenorm_k<true><<<2048, 256, 0, stream>>>(x, x0, lambdas, xn_b);
  gemm_qkv<<<dim3(16, 16, 3), 256, 0, stream>>>(xn_b, wq_b, wk_b, wv_b, q_b, k_b, v_b, vi, lamb);
  rope_k<<<16384, 256, 0, stream>>>(q_b, k_b);
  vt_k<<<dim3(128, 16), 256, 0, stream>>>(v_b, vt_b);
  attn_k<<<dim3(32, 16), 256, 0, stream>>>(q_b, k_b, vt_b, y_b);
  gemm_ep<2><<<dim3(16, 16, 2), 256, 0, stream>>>(y_b, wo_b, (void*)part, DD, DD, 1024);
  wo_red_prenorm<<<2048, 256, 0, stream>>>(part, a_f, an_b);
  gemm_ep<3><<<dim3(64, 16, 1), 256, 0, stream>>>(an_b, wfc_b, (void*)h_b, 4 * DD, DD, DD);
  gemm_ep<2><<<dim3(16, 16, 2), 256, 0, stream>>>(h_b, wpj_b, (void*)part, DD, 4 * DD, 4096);
  proj_red<<<2048, 256, 0, stream>>>(part, a_f, out);
}

// Round 3
// 440.441 us; speedup vs baseline: 1.6007x; 1.1272x over previous
//
#include <hip/hip_runtime.h>
#include <hip/hip_bf16.h>

typedef __bf16 bf16;
typedef __bf16 bf16x8 __attribute__((ext_vector_type(8)));
typedef float f32x4 __attribute__((ext_vector_type(4)));

#define DD 2048
#define DD2 4194304ull
#define G8_LDS 147456
#define G8_BUF 24576   // elems per pipeline buffer (A 16384 + B 8192)

__device__ __forceinline__ void glds16(const void* g, void* l) {
  __builtin_amdgcn_global_load_lds((const __attribute__((address_space(1))) void*)g,
                                   (__attribute__((address_space(3))) void*)l, 16, 0, 0);
}

__device__ __forceinline__ f32x4 mfma16(bf16x8 a, bf16x8 b, f32x4 c) {
  return __builtin_amdgcn_mfma_f32_16x16x32_bf16(a, b, c, 0, 0, 0);
}

// ---------------- fp32 -> bf16 convert ----------------
__global__ __launch_bounds__(256) void cvt_bf16(const float* __restrict__ in, bf16* __restrict__ out) {
  size_t i = ((size_t)blockIdx.x * 256 + threadIdx.x) * 8;
  float4 a = *(const float4*)(in + i);
  float4 b = *(const float4*)(in + i + 4);
  bf16x8 o;
  o[0] = (bf16)a.x; o[1] = (bf16)a.y; o[2] = (bf16)a.z; o[3] = (bf16)a.w;
  o[4] = (bf16)b.x; o[5] = (bf16)b.y; o[6] = (bf16)b.z; o[7] = (bf16)b.w;
  *(bf16x8*)(out + i) = o;
}

// ---------------- RMSNorm (optionally blended), fp32 in -> bf16 out ----------------
template<bool BLEND>
__global__ __launch_bounds__(256) void prenorm_k(const float* __restrict__ x, const float* __restrict__ x0,
                                                 const float* __restrict__ lambdas, bf16* __restrict__ out) {
  const int t = blockIdx.x, tid = threadIdx.x;
  const float4* xr = (const float4*)(x + (size_t)t * DD);
  float4 a0 = xr[2 * tid], a1 = xr[2 * tid + 1];
  float v[8] = {a0.x, a0.y, a0.z, a0.w, a1.x, a1.y, a1.z, a1.w};
  if (BLEND) {
    const float l0 = lambdas[0], l1 = lambdas[1];
    const float4* yr = (const float4*)(x0 + (size_t)t * DD);
    float4 b0 = yr[2 * tid], b1 = yr[2 * tid + 1];
    float w[8] = {b0.x, b0.y, b0.z, b0.w, b1.x, b1.y, b1.z, b1.w};
#pragma unroll
    for (int i = 0; i < 8; ++i) v[i] = l0 * v[i] + l1 * w[i];
  }
  float ss = 0.f;
#pragma unroll
  for (int i = 0; i < 8; ++i) ss += v[i] * v[i];
#pragma unroll
  for (int off = 1; off < 64; off <<= 1) ss += __shfl_xor(ss, off, 64);
  __shared__ float red[4];
  const int wid = tid >> 6;
  if ((tid & 63) == 0) red[wid] = ss;
  __syncthreads();
  ss = red[0] + red[1] + red[2] + red[3];
  const float sc = rsqrtf(ss * (1.0f / DD) + 1.1920928955078125e-07f);
  bf16x8 o;
#pragma unroll
  for (int i = 0; i < 8; ++i) o[i] = (bf16)(v[i] * sc);
  *(bf16x8*)(out + (size_t)t * DD + tid * 8) = o;
}

// ---------------- per-(t,h) RMSNorm + rotary, in-place on bf16 q/k ----------------
__global__ __launch_bounds__(256) void rope_k(bf16* __restrict__ qg, bf16* __restrict__ kg) {
  const int tid = threadIdx.x, lane = tid & 63, wid = tid >> 6;
  const int p = blockIdx.x * 4 + wid;          // [arr(2)][t(2048)][h(16)]
  bf16* base = ((p >> 15) ? kg : qg);
  const int t = (p >> 4) & 2047, hh = p & 15;
  base += (size_t)t * DD + hh * 128;
  float x1 = (float)base[lane], x2 = (float)base[lane + 64];
  float ss = x1 * x1 + x2 * x2;
#pragma unroll
  for (int off = 1; off < 64; off <<= 1) ss += __shfl_xor(ss, off, 64);
  const float sc = rsqrtf(ss * (1.0f / 128.0f) + 1.1920928955078125e-07f);
  x1 *= sc; x2 *= sc;
  const float fr = (float)t * exp2f((float)lane * (-13.287712379549449f / 64.0f));
  const float s = sinf(fr), c = cosf(fr);
  base[lane]      = (bf16)(x1 * c + x2 * s);
  base[lane + 64] = (bf16)(-x1 * s + x2 * c);
}

// ---------------- V transpose: v[t][2048] -> vt[d2][t] ----------------
__global__ __launch_bounds__(256) void vt_k(const bf16* __restrict__ v, bf16* __restrict__ vt) {
  __shared__ alignas(16) bf16 tile[16 * 128];
  const int tb = blockIdx.x, hb = blockIdx.y, tid = threadIdx.x;
  glds16(v + (size_t)(tb * 16 + (tid >> 4)) * DD + hb * 128 + (tid & 15) * 8, tile + tid * 8);
  __syncthreads();
  const int d_l = tid & 127, tc = tid >> 7;
  bf16x8 o;
#pragma unroll
  for (int i = 0; i < 8; ++i) o[i] = tile[(tc * 8 + i) * 128 + d_l];
  *(bf16x8*)(vt + (size_t)(hb * 128 + d_l) * DD + tb * 16 + tc * 8) = o;
}

// ================ 256x128-tile, 3-deep-pipelined GEMM (counted vmcnt) ================
// 4 waves (2x2), per-wave 128x64, BK=64. LDS: 3 rotating buffers of (A[256][64]+B[128][64]).
// Staging tile t+2 during tile t (never into a buffer being read). One vmcnt(12)/tile.
__device__ __forceinline__ void g8_stageA(const bf16* A, int Kstride, int row0, int k0,
                                          bf16* buf, int tid, int i) {
  int e = tid + i * 256, row = e >> 3, slot = e & 7;
  glds16(A + (size_t)(row0 + row) * Kstride + k0 + ((slot ^ (row & 7)) * 8), buf + e * 8);
}
__device__ __forceinline__ void g8_stageB(const bf16* B, int Kstride, int col0, int k0,
                                          bf16* buf, int tid, int i) {
  int e = tid + i * 256, row = e >> 3, slot = e & 7;
  glds16(B + (size_t)(col0 + row) * Kstride + k0 + ((slot ^ (row & 7)) * 8), buf + 16384 + e * 8);
}

__device__ __forceinline__ void gemm8_core(const bf16* __restrict__ A, const bf16* __restrict__ B,
                                           int Kstride, int Klen, int row0, int col0,
                                           bf16* smem, f32x4 (&acc)[8][4]) {
  const int tid = threadIdx.x, lane = tid & 63, wid = tid >> 6;
  const int wm = wid >> 1, wn = wid & 1;
  const int l15 = lane & 15, g = lane >> 4;
  const int NT = Klen >> 6;
  // prologue: stage tiles 0,1 into buffers 0,1
#pragma unroll
  for (int i = 0; i < 8; ++i) g8_stageA(A, Kstride, row0, 0, smem, tid, i);
#pragma unroll
  for (int i = 0; i < 4; ++i) g8_stageB(B, Kstride, col0, 0, smem, tid, i);
#pragma unroll
  for (int i = 0; i < 8; ++i) g8_stageA(A, Kstride, row0, 64, smem + G8_BUF, tid, i);
#pragma unroll
  for (int i = 0; i < 4; ++i) g8_stageB(B, Kstride, col0, 64, smem + G8_BUF, tid, i);
  asm volatile("s_waitcnt vmcnt(12)" ::: "memory");   // tile 0 fully landed
  __builtin_amdgcn_s_barrier();

  int cur = 0, sb = 2;
  for (int t = 0; t < NT; ++t) {
    bf16* Ab = smem + cur * G8_BUF;
    bf16* Bb = Ab + 16384;
    bf16* Sb = smem + sb * G8_BUF;
    const int ks0 = (t + 2) * 64;
    const bool st = (t + 2) < NT;
    bf16x8 a[4][2], b0[2][2], b1[2][2];
    // ---- PH1: Q(0,0): read a(qm=0), b0(qn=0); stage A0-2 of t+2
#pragma unroll
    for (int mm = 0; mm < 4; ++mm)
#pragma unroll
      for (int ks = 0; ks < 2; ++ks) {
        int row = wm * 128 + mm * 16 + l15;
        a[mm][ks] = *(const bf16x8*)(Ab + row * 64 + (((ks * 4 + g) ^ (row & 7)) * 8));
      }
#pragma unroll
    for (int nn = 0; nn < 2; ++nn)
#pragma unroll
      for (int ks = 0; ks < 2; ++ks) {
        int row = wn * 64 + nn * 16 + l15;
        b0[nn][ks] = *(const bf16x8*)(Bb + row * 64 + (((ks * 4 + g) ^ (row & 7)) * 8));
      }
    if (st) { g8_stageA(A, Kstride, row0, ks0, Sb, tid, 0);
              g8_stageA(A, Kstride, row0, ks0, Sb, tid, 1);
              g8_stageA(A, Kstride, row0, ks0, Sb, tid, 2); }
    __builtin_amdgcn_s_setprio(1);
#pragma unroll
    for (int mm = 0; mm < 4; ++mm)
#pragma unroll
      for (int nn = 0; nn < 2; ++nn)
#pragma unroll
        for (int ks = 0; ks < 2; ++ks)
          acc[mm][nn] = mfma16(a[mm][ks], b0[nn][ks], acc[mm][nn]);
    __builtin_amdgcn_s_setprio(0);
    __builtin_amdgcn_s_barrier();
    // ---- PH2: Q(0,1): read b1(qn=1); stage A3-5
#pragma unroll
    for (int nn = 0; nn < 2; ++nn)
#pragma unroll
      for (int ks = 0; ks < 2; ++ks) {
        int row = wn * 64 + 32 + nn * 16 + l15;
        b1[nn][ks] = *(const bf16x8*)(Bb + row * 64 + (((ks * 4 + g) ^ (row & 7)) * 8));
      }
    if (st) { g8_stageA(A, Kstride, row0, ks0, Sb, tid, 3);
              g8_stageA(A, Kstride, row0, ks0, Sb, tid, 4);
              g8_stageA(A, Kstride, row0, ks0, Sb, tid, 5); }
    __builtin_amdgcn_s_setprio(1);
#pragma unroll
    for (int mm = 0; mm < 4; ++mm)
#pragma unroll
      for (int nn = 0; nn < 2; ++nn)
#pragma unroll
        for (int ks = 0; ks < 2; ++ks)
          acc[mm][2 + nn] = mfma16(a[mm][ks], b1[nn][ks], acc[mm][2 + nn]);
    __builtin_amdgcn_s_setprio(0);
    __builtin_amdgcn_s_barrier();
    // ---- PH3: Q(1,0): read a(qm=1); stage A6,A7,B0
#pragma unroll
    for (int mm = 0; mm < 4; ++mm)
#pragma unroll
      for (int ks = 0; ks < 2; ++ks) {
        int row = wm * 128 + 64 + mm * 16 + l15;
        a[mm][ks] = *(const bf16x8*)(Ab + row * 64 + (((ks * 4 + g) ^ (row & 7)) * 8));
      }
    if (st) { g8_stageA(A, Kstride, row0, ks0, Sb, tid, 6);
              g8_stageA(A, Kstride, row0, ks0, Sb, tid, 7);
              g8_stageB(B, Kstride, col0, ks0, Sb, tid, 0); }
    __builtin_amdgcn_s_setprio(1);
#pragma unroll
    for (int mm = 0; mm < 4; ++mm)
#pragma unroll
      for (int nn = 0; nn < 2; ++nn)
#pragma unroll
        for (int ks = 0; ks < 2; ++ks)
          acc[4 + mm][nn] = mfma16(a[mm][ks], b0[nn][ks], acc[4 + mm][nn]);
    __builtin_amdgcn_s_setprio(0);
    __builtin_amdgcn_s_barrier();
    // ---- PH4: Q(1,1): stage B1-3; counted wait
    if (st) { g8_stageB(B, Kstride, col0, ks0, Sb, tid, 1);
              g8_stageB(B, Kstride, col0, ks0, Sb, tid, 2);
              g8_stageB(B, Kstride, col0, ks0, Sb, tid, 3); }
    __builtin_amdgcn_s_setprio(1);
#pragma unroll
    for (int mm = 0; mm < 4; ++mm)
#pragma unroll
      for (int nn = 0; nn < 2; ++nn)
#pragma unroll
        for (int ks = 0; ks < 2; ++ks)
          acc[4 + mm][2 + nn] = mfma16(a[mm][ks], b1[nn][ks], acc[4 + mm][2 + nn]);
    __builtin_amdgcn_s_setprio(0);
    if (st) { asm volatile("s_waitcnt vmcnt(12)" ::: "memory"); }        // t+1 landed
    else if (t + 1 < NT) { asm volatile("s_waitcnt vmcnt(0)" ::: "memory"); }
    __builtin_amdgcn_s_barrier();
    cur = (cur == 2) ? 0 : cur + 1;
    sb = (sb == 2) ? 0 : sb + 1;
  }
}

// D layout per fragment: row += g*4+j, col += l15
#define GEMM8_EPI(STMT)                                                       \
  { const int lane_ = threadIdx.x & 63, wid_ = threadIdx.x >> 6;              \
    const int l15_ = lane_ & 15, g_ = lane_ >> 4;                             \
    const int wr_ = (wid_ >> 1) * 128, wc_ = (wid_ & 1) * 64;                 \
    _Pragma("unroll") for (int m = 0; m < 8; ++m)                             \
    _Pragma("unroll") for (int n = 0; n < 4; ++n)                             \
    _Pragma("unroll") for (int j = 0; j < 4; ++j) {                           \
      int grow = row0 + wr_ + m * 16 + g_ * 4 + j;                            \
      int gcol = col0 + wc_ + n * 16 + l15_;                                  \
      float vacc = acc[m][n][j];                                              \
      STMT; } }

__global__ __launch_bounds__(256, 1) void gemm8_qkv(const bf16* __restrict__ A,
    const bf16* __restrict__ Wq, const bf16* __restrict__ Wk, const bf16* __restrict__ Wv,
    bf16* __restrict__ oq, bf16* __restrict__ ok, bf16* __restrict__ ov,
    const float* __restrict__ vi, const float* __restrict__ lambp) {
  extern __shared__ bf16 smem8[];
  const int z = blockIdx.z;
  const bf16* B = (z == 0) ? Wq : (z == 1) ? Wk : Wv;
  bf16* out = (z == 0) ? oq : (z == 1) ? ok : ov;
  const int row0 = blockIdx.y * 256, col0 = blockIdx.x * 128;
  f32x4 acc[8][4] = {};
  gemm8_core(A, B, DD, DD, row0, col0, smem8, acc);
  if (z < 2) {
    GEMM8_EPI( out[(size_t)grow * DD + gcol] = (bf16)vacc; )
  } else {
    const float lam = *lambp;
    GEMM8_EPI( out[(size_t)grow * DD + gcol] =
                 (bf16)((1.0f - lam) * vacc + lam * vi[(size_t)grow * DD + gcol]); )
  }
}

// EPI: 2 = f32 partial store (split-K via blockIdx.z), 3 = relu^2 -> bf16
template<int EPI>
__global__ __launch_bounds__(256, 1) void gemm8_ep(const bf16* __restrict__ A, const bf16* __restrict__ B,
                                                   void* __restrict__ outv, int N, int Kstride, int Klen) {
  extern __shared__ bf16 smem8[];
  const int row0 = blockIdx.y * 256, col0 = blockIdx.x * 128;
  const int kofs = blockIdx.z * Klen;
  f32x4 acc[8][4] = {};
  gemm8_core(A + kofs, B + kofs, Kstride, Klen, row0, col0, smem8, acc);
  if (EPI == 2) { float* out = (float*)outv + (size_t)blockIdx.z * DD2;
    GEMM8_EPI( out[(size_t)grow * N + gcol] = vacc; ) }
  if (EPI == 3) { bf16* out = (bf16*)outv;
    GEMM8_EPI( float r = fmaxf(vacc, 0.f); out[(size_t)grow * N + gcol] = (bf16)(r * r); ) }
}

// ---------------- split-K reduces ----------------
__global__ __launch_bounds__(256) void wo_red_prenorm(const float* __restrict__ p, float* __restrict__ a_f,
                                                      bf16* __restrict__ an) {
  const int t = blockIdx.x, tid = threadIdx.x;
  const size_t base = (size_t)t * DD + tid * 8;
  float4 a0 = *(const float4*)(p + base),        a1 = *(const float4*)(p + base + 4);
  float4 b0 = *(const float4*)(p + DD2 + base),  b1 = *(const float4*)(p + DD2 + base + 4);
  float v[8] = {a0.x + b0.x, a0.y + b0.y, a0.z + b0.z, a0.w + b0.w,
                a1.x + b1.x, a1.y + b1.y, a1.z + b1.z, a1.w + b1.w};
  *(float4*)(a_f + base)     = make_float4(v[0], v[1], v[2], v[3]);
  *(float4*)(a_f + base + 4) = make_float4(v[4], v[5], v[6], v[7]);
  float ss = 0.f;
#pragma unroll
  for (int i = 0; i < 8; ++i) ss += v[i] * v[i];
#pragma unroll
  for (int off = 1; off < 64; off <<= 1) ss += __shfl_xor(ss, off, 64);
  __shared__ float red[4];
  if ((tid & 63) == 0) red[tid >> 6] = ss;
  __syncthreads();
  ss = red[0] + red[1] + red[2] + red[3];
  const float sc = rsqrtf(ss * (1.0f / DD) + 1.1920928955078125e-07f);
  bf16x8 o;
#pragma unroll
  for (int i = 0; i < 8; ++i) o[i] = (bf16)(v[i] * sc);
  *(bf16x8*)(an + base) = o;
}

__global__ __launch_bounds__(256) void proj_red(const float* __restrict__ p, const float* __restrict__ a_f,
                                                float* __restrict__ out) {
  const size_t base = ((size_t)blockIdx.x * 256 + threadIdx.x) * 8;
#pragma unroll
  for (int h = 0; h < 2; ++h) {
    size_t i = base + h * 4;
    float4 r = *(const float4*)(a_f + i);
    float4 u = *(const float4*)(p + i);
    float4 w = *(const float4*)(p + DD2 + i);
    *(float4*)(out + i) = make_float4(r.x + u.x + w.x, r.y + u.y + w.y,
                                      r.z + u.z + w.z, r.w + u.w + w.w);
  }
}

// ---------------- causal flash attention, no-max softmax ----------------
__global__ __launch_bounds__(256) void attn_k(const bf16* __restrict__ qg, const bf16* __restrict__ kg,
                                              const bf16* __restrict__ vtg, bf16* __restrict__ yg) {
  __shared__ alignas(16) bf16 Ks[32 * 128];
  __shared__ alignas(16) bf16 Vt[128 * 32];
  __shared__ alignas(16) bf16 Pl[4][16 * 32];
  const int h = blockIdx.y, qb = 31 - blockIdx.x;
  const int tid = threadIdx.x, lane = tid & 63, wid = tid >> 6;
  const int l15 = lane & 15, g = lane >> 4;
  const int qrow = qb * 64 + wid * 16;
  const float scale = 0.08838834764831845f;
  bf16x8 aQ[4];
  {
    const bf16* qp = qg + (size_t)(qrow + l15) * DD + h * 128 + g * 8;
#pragma unroll
    for (int kc = 0; kc < 4; ++kc) aQ[kc] = *(const bf16x8*)(qp + kc * 32);
  }
  f32x4 acc[8] = {};
  f32x4 l4 = {0.f, 0.f, 0.f, 0.f};
  const int nkt = qb * 2 + 2;
  for (int kt = 0; kt < nkt; ++kt) {
    const int kbase = kt * 32;
    __syncthreads();
#pragma unroll
    for (int r = 0; r < 2; ++r) {
      int e = tid + r * 256;
      int row = e >> 4, slot = e & 15;
      glds16(kg + (size_t)(kbase + row) * DD + h * 128 + ((slot ^ (row & 7)) * 8), Ks + e * 8);
    }
#pragma unroll
    for (int r = 0; r < 2; ++r) {
      int e = tid + r * 256;
      int d = e >> 2, slot = e & 3;
      glds16(vtg + (size_t)(h * 128 + d) * DD + kbase + ((slot ^ (d & 3)) * 8), Vt + e * 8);
    }
    __syncthreads();
    f32x4 S0 = {}, S1 = {};
#pragma unroll
    for (int kc = 0; kc < 4; ++kc) {
      int r0 = l15, r1 = 16 + l15;
      bf16x8 b0 = *(const bf16x8*)(Ks + r0 * 128 + (((kc * 4 + g) ^ (r0 & 7)) * 8));
      bf16x8 b1 = *(const bf16x8*)(Ks + r1 * 128 + (((kc * 4 + g) ^ (r1 & 7)) * 8));
      S0 = mfma16(aQ[kc], b0, S0);
      S1 = mfma16(aQ[kc], b1, S1);
    }
    const int k0i = kbase + l15, k1i = k0i + 16;
    f32x4 p0, p1;
#pragma unroll
    for (int j = 0; j < 4; ++j) {
      int q = qrow + g * 4 + j;
      p0[j] = (k0i <= q) ? __expf(S0[j] * scale) : 0.f;
      p1[j] = (k1i <= q) ? __expf(S1[j] * scale) : 0.f;
      l4[j] += p0[j] + p1[j];
    }
    const int c0 = (l15 >> 3) ^ g, c1 = (2 + (l15 >> 3)) ^ g, w7 = l15 & 7;
#pragma unroll
    for (int j = 0; j < 4; ++j) {
      Pl[wid][(g * 4 + j) * 32 + c0 * 8 + w7] = (bf16)p0[j];
      Pl[wid][(g * 4 + j) * 32 + c1 * 8 + w7] = (bf16)p1[j];
    }
    bf16x8 aP = *(const bf16x8*)(&Pl[wid][l15 * 32 + ((g ^ (l15 >> 2)) * 8)]);
#pragma unroll
    for (int dt = 0; dt < 8; ++dt) {
      int d = dt * 16 + l15;
      bf16x8 bV = *(const bf16x8*)(Vt + d * 32 + ((g ^ (d & 3)) * 8));
      acc[dt] = mfma16(aP, bV, acc[dt]);
    }
  }
#pragma unroll
  for (int off = 1; off < 16; off <<= 1)
#pragma unroll
    for (int j = 0; j < 4; ++j) l4[j] += __shfl_xor(l4[j], off, 64);
#pragma unroll
  for (int dt = 0; dt < 8; ++dt)
#pragma unroll
    for (int j = 0; j < 4; ++j) {
      int q = qrow + g * 4 + j;
      yg[(size_t)q * DD + h * 128 + dt * 16 + l15] = (bf16)(acc[dt][j] / l4[j]);
    }
}

extern "C" void kernel_launch(void* const* d_in, const int* in_sizes, int n_in,
                              void* d_out, int out_size, void* d_ws, size_t ws_size,
                              hipStream_t stream) {
  const float* x       = (const float*)d_in[0];
  const float* vi      = (const float*)d_in[1];
  const float* x0      = (const float*)d_in[2];
  const float* wq      = (const float*)d_in[3];
  const float* wk      = (const float*)d_in[4];
  const float* wv      = (const float*)d_in[5];
  const float* wo      = (const float*)d_in[6];
  const float* lamb    = (const float*)d_in[7];
  const float* lambdas = (const float*)d_in[8];
  const float* wfc     = (const float*)d_in[9];
  const float* wproj   = (const float*)d_in[10];
  float* out = (float*)d_out;

  (void)hipFuncSetAttribute(reinterpret_cast<const void*>(gemm8_qkv),
                            hipFuncAttributeMaxDynamicSharedMemorySize, G8_LDS);
  (void)hipFuncSetAttribute(reinterpret_cast<const void*>(gemm8_ep<2>),
                            hipFuncAttributeMaxDynamicSharedMemorySize, G8_LDS);
  (void)hipFuncSetAttribute(reinterpret_cast<const void*>(gemm8_ep<3>),
                            hipFuncAttributeMaxDynamicSharedMemorySize, G8_LDS);

  char* wsb = (char*)d_ws;
  size_t off = 0;
  auto alloc = [&](size_t bytes) { void* p = wsb + off; off = (off + bytes + 255) & ~(size_t)255; return p; };
  bf16* wq_b  = (bf16*)alloc(DD2 * 2);
  bf16* wk_b  = (bf16*)alloc(DD2 * 2);
  bf16* wv_b  = (bf16*)alloc(DD2 * 2);
  bf16* wo_b  = (bf16*)alloc(DD2 * 2);
  bf16* wfc_b = (bf16*)alloc(DD2 * 8);
  bf16* wpj_b = (bf16*)alloc(DD2 * 8);
  bf16* xn_b  = (bf16*)alloc(DD2 * 2);
  bf16* q_b   = (bf16*)alloc(DD2 * 2);
  bf16* k_b   = (bf16*)alloc(DD2 * 2);
  bf16* v_b   = (bf16*)alloc(DD2 * 2);
  float* part = (float*)xn_b;            // alias: 2 x DD2 f32 = exactly xn..v
  bf16* y_b   = (bf16*)alloc(DD2 * 2);
  float* a_f  = (float*)alloc(DD2 * 4);
  bf16* an_b  = (bf16*)alloc(DD2 * 2);
  bf16* h_b   = (bf16*)alloc(DD2 * 8);
  bf16* vt_b  = h_b;                     // alias: vt dead before fc writes h

  cvt_bf16<<<2048, 256, 0, stream>>>(wq, wq_b);
  cvt_bf16<<<2048, 256, 0, stream>>>(wk, wk_b);
  cvt_bf16<<<2048, 256, 0, stream>>>(wv, wv_b);
  cvt_bf16<<<2048, 256, 0, stream>>>(wo, wo_b);
  cvt_bf16<<<8192, 256, 0, stream>>>(wfc, wfc_b);
  cvt_bf16<<<8192, 256, 0, stream>>>(wproj, wpj_b);

  prenorm_k<true><<<2048, 256, 0, stream>>>(x, x0, lambdas, xn_b);
  gemm8_qkv<<<dim3(16, 8, 3), 256, G8_LDS, stream>>>(xn_b, wq_b, wk_b, wv_b, q_b, k_b, v_b, vi, lamb);
  rope_k<<<16384, 256, 0, stream>>>(q_b, k_b);
  vt_k<<<dim3(128, 16), 256, 0, stream>>>(v_b, vt_b);
  attn_k<<<dim3(32, 16), 256, 0, stream>>>(q_b, k_b, vt_b, y_b);
  gemm8_ep<2><<<dim3(16, 8, 2), 256, G8_LDS, stream>>>(y_b, wo_b, (void*)part, DD, DD, 1024);
  wo_red_prenorm<<<2048, 256, 0, stream>>>(part, a_f, an_b);
  gemm8_ep<3><<<dim3(64, 8, 1), 256, G8_LDS, stream>>>(an_b, wfc_b, (void*)h_b, 4 * DD, DD, DD);
  gemm8_ep<2><<<dim3(16, 8, 2), 256, G8_LDS, stream>>>(h_b, wpj_b, (void*)part, DD, 4 * DD, 4096);
  proj_red<<<2048, 256, 0, stream>>>(part, a_f, out);
}

// Round 4
// 407.217 us; speedup vs baseline: 1.7313x; 1.0816x over previous
//
#include <hip/hip_runtime.h>
#include <hip/hip_bf16.h>

typedef __bf16 bf16;
typedef __bf16 bf16x8 __attribute__((ext_vector_type(8)));
typedef float f32x4 __attribute__((ext_vector_type(4)));

#define DD 2048
#define DD2 4194304ull
#define G9_LDS 131072   // 2 buffers x (A[256][64] + B[256][64]) bf16

__device__ __forceinline__ void glds16(const void* g, void* l) {
  __builtin_amdgcn_global_load_lds((const __attribute__((address_space(1))) void*)g,
                                   (__attribute__((address_space(3))) void*)l, 16, 0, 0);
}

__device__ __forceinline__ f32x4 mfma16(bf16x8 a, bf16x8 b, f32x4 c) {
  return __builtin_amdgcn_mfma_f32_16x16x32_bf16(a, b, c, 0, 0, 0);
}

// ---------------- fused fp32 -> bf16 convert of all 6 weights ----------------
__global__ __launch_bounds__(256) void cvt_all(const float* __restrict__ s0, const float* __restrict__ s1,
                                               const float* __restrict__ s2, const float* __restrict__ s3,
                                               const float* __restrict__ s4, const float* __restrict__ s5,
                                               bf16* __restrict__ dbase) {
  const int b = blockIdx.x;
  const float* src; bf16* dst; int lb;
  if (b < 8192)       { int r = b >> 11; src = (r == 0) ? s0 : (r == 1) ? s1 : (r == 2) ? s2 : s3;
                        dst = dbase + (size_t)r * DD2; lb = b & 2047; }
  else if (b < 16384) { src = s4; dst = dbase + 4 * DD2; lb = b - 8192; }
  else                { src = s5; dst = dbase + 8 * DD2; lb = b - 16384; }
  size_t i = ((size_t)lb * 256 + threadIdx.x) * 8;
  float4 a = *(const float4*)(src + i);
  float4 c = *(const float4*)(src + i + 4);
  bf16x8 o;
  o[0] = (bf16)a.x; o[1] = (bf16)a.y; o[2] = (bf16)a.z; o[3] = (bf16)a.w;
  o[4] = (bf16)c.x; o[5] = (bf16)c.y; o[6] = (bf16)c.z; o[7] = (bf16)c.w;
  *(bf16x8*)(dst + i) = o;
}

// ---------------- RMSNorm (optionally blended), fp32 in -> bf16 out ----------------
template<bool BLEND>
__global__ __launch_bounds__(256) void prenorm_k(const float* __restrict__ x, const float* __restrict__ x0,
                                                 const float* __restrict__ lambdas, bf16* __restrict__ out) {
  const int t = blockIdx.x, tid = threadIdx.x;
  const float4* xr = (const float4*)(x + (size_t)t * DD);
  float4 a0 = xr[2 * tid], a1 = xr[2 * tid + 1];
  float v[8] = {a0.x, a0.y, a0.z, a0.w, a1.x, a1.y, a1.z, a1.w};
  if (BLEND) {
    const float l0 = lambdas[0], l1 = lambdas[1];
    const float4* yr = (const float4*)(x0 + (size_t)t * DD);
    float4 b0 = yr[2 * tid], b1 = yr[2 * tid + 1];
    float w[8] = {b0.x, b0.y, b0.z, b0.w, b1.x, b1.y, b1.z, b1.w};
#pragma unroll
    for (int i = 0; i < 8; ++i) v[i] = l0 * v[i] + l1 * w[i];
  }
  float ss = 0.f;
#pragma unroll
  for (int i = 0; i < 8; ++i) ss += v[i] * v[i];
#pragma unroll
  for (int off = 1; off < 64; off <<= 1) ss += __shfl_xor(ss, off, 64);
  __shared__ float red[4];
  const int wid = tid >> 6;
  if ((tid & 63) == 0) red[wid] = ss;
  __syncthreads();
  ss = red[0] + red[1] + red[2] + red[3];
  const float sc = rsqrtf(ss * (1.0f / DD) + 1.1920928955078125e-07f);
  bf16x8 o;
#pragma unroll
  for (int i = 0; i < 8; ++i) o[i] = (bf16)(v[i] * sc);
  *(bf16x8*)(out + (size_t)t * DD + tid * 8) = o;
}

// ---------------- per-(t,h) RMSNorm + rotary, in-place on bf16 q/k ----------------
__global__ __launch_bounds__(256) void rope_k(bf16* __restrict__ qg, bf16* __restrict__ kg) {
  const int tid = threadIdx.x, lane = tid & 63, wid = tid >> 6;
  const int p = blockIdx.x * 4 + wid;          // [arr(2)][t(2048)][h(16)]
  bf16* base = ((p >> 15) ? kg : qg);
  const int t = (p >> 4) & 2047, hh = p & 15;
  base += (size_t)t * DD + hh * 128;
  float x1 = (float)base[lane], x2 = (float)base[lane + 64];
  float ss = x1 * x1 + x2 * x2;
#pragma unroll
  for (int off = 1; off < 64; off <<= 1) ss += __shfl_xor(ss, off, 64);
  const float sc = rsqrtf(ss * (1.0f / 128.0f) + 1.1920928955078125e-07f);
  x1 *= sc; x2 *= sc;
  const float fr = (float)t * exp2f((float)lane * (-13.287712379549449f / 64.0f));
  const float s = sinf(fr), c = cosf(fr);
  base[lane]      = (bf16)(x1 * c + x2 * s);
  base[lane + 64] = (bf16)(-x1 * s + x2 * c);
}

// ---------------- V transpose: v[t][2048] -> vt[d2][t] ----------------
__global__ __launch_bounds__(256) void vt_k(const bf16* __restrict__ v, bf16* __restrict__ vt) {
  __shared__ alignas(16) bf16 tile[16 * 128];
  const int tb = blockIdx.x, hb = blockIdx.y, tid = threadIdx.x;
  glds16(v + (size_t)(tb * 16 + (tid >> 4)) * DD + hb * 128 + (tid & 15) * 8, tile + tid * 8);
  __syncthreads();
  const int d_l = tid & 127, tc = tid >> 7;
  bf16x8 o;
#pragma unroll
  for (int i = 0; i < 8; ++i) o[i] = tile[(tc * 8 + i) * 128 + d_l];
  *(bf16x8*)(vt + (size_t)(hb * 128 + d_l) * DD + tb * 16 + tc * 8) = o;
}

// ================ 256x256-tile, 8-wave, phase-interleaved GEMM ================
// 8 waves (2M x 4N), per-wave 128x64, BK=64. LDS: 2 buffers, each A[256][64]+B[256][64].
// A stored as [hm-half][128][64]: physical row pr = hm*128 + wm*64 + (R&63); B as
// [hn-half][128][64]: pb = hn*128 + wn*32 + (C&31). 16B slots XOR-swizzled by (p&7).
// Stage units (2 glds/thread each) issued one-per-phase into the other buffer in
// consumption order U0=Ah0,U2=Bh0,U3=Bh1,U1=Ah1 -> vmcnt(4) before PH1..PH3 is exact.
__device__ __forceinline__ void g9_stageA(const bf16* A, int Kstride, int row0, int k0,
                                          bf16* buf, int hm, int tid) {
#pragma unroll
  for (int i = 0; i < 2; ++i) {
    int e = tid + i * 512;                 // [0,1024): prl = e>>3, slot = e&7
    int prl = e >> 3, slot = e & 7;
    int wm = prl >> 6, r63 = prl & 63;
    glds16(A + (size_t)(row0 + wm * 128 + hm * 64 + r63) * Kstride + k0 + ((slot ^ (prl & 7)) * 8),
           buf + hm * 8192 + e * 8);
  }
}
__device__ __forceinline__ void g9_stageB(const bf16* B, int Kstride, int col0, int k0,
                                          bf16* buf, int hn, int tid) {
#pragma unroll
  for (int i = 0; i < 2; ++i) {
    int e = tid + i * 512;
    int pbl = e >> 3, slot = e & 7;
    int wn = pbl >> 5, q = pbl & 31;
    glds16(B + (size_t)(col0 + wn * 64 + hn * 32 + q) * Kstride + k0 + ((slot ^ (pbl & 7)) * 8),
           buf + 16384 + hn * 8192 + e * 8);
  }
}

__device__ __forceinline__ void gemm9_core(const bf16* __restrict__ A, const bf16* __restrict__ B,
                                           int Kstride, int Klen, int row0, int col0,
                                           bf16* smem, f32x4 (&acc)[8][4]) {
  const int tid = threadIdx.x, lane = tid & 63, wid = tid >> 6;
  const int wm = wid >> 2, wn = wid & 3;
  const int l15 = lane & 15, g = lane >> 4;
  const int sw = l15 & 7;
  const int NT = Klen >> 6;
  // prologue: tile 0 in consumption order
  g9_stageA(A, Kstride, row0, 0, smem, 0, tid);
  g9_stageB(B, Kstride, col0, 0, smem, 0, tid);
  g9_stageB(B, Kstride, col0, 0, smem, 1, tid);
  g9_stageA(A, Kstride, row0, 0, smem, 1, tid);

  bf16x8 a[4][2], b0[2][2], b1[2][2];
  for (int t = 0; t < NT; ++t) {
    bf16* cb = smem + (t & 1) * 32768;
    bf16* sb = smem + ((t + 1) & 1) * 32768;
    const int ks0 = (t + 1) << 6;
    const bool st = (t + 1) < NT;
    // ---- PH1: quadrant (hm0, hn0); stage U0^{t+1}
    asm volatile("s_waitcnt vmcnt(4)" ::: "memory");
    __builtin_amdgcn_s_barrier();
#pragma unroll
    for (int mm = 0; mm < 4; ++mm)
#pragma unroll
      for (int ks = 0; ks < 2; ++ks) {
        int pr = wm * 64 + mm * 16 + l15;
        a[mm][ks] = *(const bf16x8*)(cb + pr * 64 + (((ks * 4 + g) ^ sw) * 8));
      }
#pragma unroll
    for (int nn = 0; nn < 2; ++nn)
#pragma unroll
      for (int ks = 0; ks < 2; ++ks) {
        int pb = wn * 32 + nn * 16 + l15;
        b0[nn][ks] = *(const bf16x8*)(cb + 16384 + pb * 64 + (((ks * 4 + g) ^ sw) * 8));
      }
    if (st) g9_stageA(A, Kstride, row0, ks0, sb, 0, tid);
    __builtin_amdgcn_s_setprio(1);
#pragma unroll
    for (int mm = 0; mm < 4; ++mm)
#pragma unroll
      for (int nn = 0; nn < 2; ++nn)
#pragma unroll
        for (int ks = 0; ks < 2; ++ks)
          acc[mm][nn] = mfma16(a[mm][ks], b0[nn][ks], acc[mm][nn]);
    __builtin_amdgcn_s_setprio(0);
    __builtin_amdgcn_s_barrier();
    // ---- PH2: quadrant (hm0, hn1); stage U2^{t+1}
    if (st) { asm volatile("s_waitcnt vmcnt(4)" ::: "memory"); }
    else    { asm volatile("s_waitcnt vmcnt(2)" ::: "memory"); }
    __builtin_amdgcn_s_barrier();
#pragma unroll
    for (int nn = 0; nn < 2; ++nn)
#pragma unroll
      for (int ks = 0; ks < 2; ++ks) {
        int pb = 128 + wn * 32 + nn * 16 + l15;
        b1[nn][ks] = *(const bf16x8*)(cb + 16384 + pb * 64 + (((ks * 4 + g) ^ sw) * 8));
      }
    if (st) g9_stageB(B, Kstride, col0, ks0, sb, 0, tid);
    __builtin_amdgcn_s_setprio(1);
#pragma unroll
    for (int mm = 0; mm < 4; ++mm)
#pragma unroll
      for (int nn = 0; nn < 2; ++nn)
#pragma unroll
        for (int ks = 0; ks < 2; ++ks)
          acc[mm][2 + nn] = mfma16(a[mm][ks], b1[nn][ks], acc[mm][2 + nn]);
    __builtin_amdgcn_s_setprio(0);
    __builtin_amdgcn_s_barrier();
    // ---- PH3: quadrant (hm1, hn0); stage U3^{t+1}
    if (st) { asm volatile("s_waitcnt vmcnt(4)" ::: "memory"); }
    else    { asm volatile("s_waitcnt vmcnt(0)" ::: "memory"); }
    __builtin_amdgcn_s_barrier();
#pragma unroll
    for (int mm = 0; mm < 4; ++mm)
#pragma unroll
      for (int ks = 0; ks < 2; ++ks) {
        int pr = 128 + wm * 64 + mm * 16 + l15;
        a[mm][ks] = *(const bf16x8*)(cb + pr * 64 + (((ks * 4 + g) ^ sw) * 8));
      }
    if (st) g9_stageB(B, Kstride, col0, ks0, sb, 1, tid);
    __builtin_amdgcn_s_setprio(1);
#pragma unroll
    for (int mm = 0; mm < 4; ++mm)
#pragma unroll
      for (int nn = 0; nn < 2; ++nn)
#pragma unroll
        for (int ks = 0; ks < 2; ++ks)
          acc[4 + mm][nn] = mfma16(a[mm][ks], b0[nn][ks], acc[4 + mm][nn]);
    __builtin_amdgcn_s_setprio(0);
    __builtin_amdgcn_s_barrier();
    // ---- PH4: quadrant (hm1, hn1); stage U1^{t+1}; no wait, no new ds_reads
    if (st) g9_stageA(A, Kstride, row0, ks0, sb, 1, tid);
    __builtin_amdgcn_s_setprio(1);
#pragma unroll
    for (int mm = 0; mm < 4; ++mm)
#pragma unroll
      for (int nn = 0; nn < 2; ++nn)
#pragma unroll
        for (int ks = 0; ks < 2; ++ks)
          acc[4 + mm][2 + nn] = mfma16(a[mm][ks], b1[nn][ks], acc[4 + mm][2 + nn]);
    __builtin_amdgcn_s_setprio(0);
    __builtin_amdgcn_s_barrier();
  }
}

// D layout: col=lane&15, row=(lane>>4)*4+j; acc[m][n]: hm=m>>2, mm=m&3, hn=n>>1, nn=n&1
#define GEMM9_EPI(STMT)                                                        \
  { const int lane_ = threadIdx.x & 63, wid_ = threadIdx.x >> 6;               \
    const int l15_ = lane_ & 15, g_ = lane_ >> 4;                              \
    const int wm_ = wid_ >> 2, wn_ = wid_ & 3;                                 \
    _Pragma("unroll") for (int m = 0; m < 8; ++m)                              \
    _Pragma("unroll") for (int n = 0; n < 4; ++n)                              \
    _Pragma("unroll") for (int j = 0; j < 4; ++j) {                            \
      int grow = row0 + wm_ * 128 + (m >> 2) * 64 + (m & 3) * 16 + g_ * 4 + j; \
      int gcol = col0 + wn_ * 64 + (n >> 1) * 32 + (n & 1) * 16 + l15_;        \
      float vacc = acc[m][n][j];                                               \
      STMT; } }

__global__ __launch_bounds__(512, 1) void gemm9_qkv(const bf16* __restrict__ A,
    const bf16* __restrict__ Wq, const bf16* __restrict__ Wk, const bf16* __restrict__ Wv,
    bf16* __restrict__ oq, bf16* __restrict__ ok, bf16* __restrict__ ov,
    const float* __restrict__ vi, const float* __restrict__ lambp) {
  extern __shared__ bf16 smem9[];
  const int z = blockIdx.z;
  const bf16* B = (z == 0) ? Wq : (z == 1) ? Wk : Wv;
  bf16* out = (z == 0) ? oq : (z == 1) ? ok : ov;
  const int row0 = blockIdx.y * 256, col0 = blockIdx.x * 256;
  f32x4 acc[8][4] = {};
  gemm9_core(A, B, DD, DD, row0, col0, smem9, acc);
  if (z < 2) {
    GEMM9_EPI( out[(size_t)grow * DD + gcol] = (bf16)vacc; )
  } else {
    const float lam = *lambp;
    GEMM9_EPI( out[(size_t)grow * DD + gcol] =
                 (bf16)((1.0f - lam) * vacc + lam * vi[(size_t)grow * DD + gcol]); )
  }
}

// EPI: 2 = f32 partial store (split-K via blockIdx.z), 3 = relu^2 -> bf16
template<int EPI>
__global__ __launch_bounds__(512, 1) void gemm9_ep(const bf16* __restrict__ A, const bf16* __restrict__ B,
                                                   void* __restrict__ outv, int N, int Kstride,
                                                   int KlenMain, int Ktot) {
  extern __shared__ bf16 smem9[];
  const int row0 = blockIdx.y * 256, col0 = blockIdx.x * 256;
  const int kofs = blockIdx.z * KlenMain;
  const int Klen = min(KlenMain, Ktot - kofs);
  f32x4 acc[8][4] = {};
  gemm9_core(A + kofs, B + kofs, Kstride, Klen, row0, col0, smem9, acc);
  if (EPI == 2) { float* out = (float*)outv + (size_t)blockIdx.z * DD2;
    GEMM9_EPI( out[(size_t)grow * N + gcol] = vacc; ) }
  if (EPI == 3) { bf16* out = (bf16*)outv;
    GEMM9_EPI( float r = fmaxf(vacc, 0.f); out[(size_t)grow * N + gcol] = (bf16)(r * r); ) }
}

// ---------------- split-K reduces ----------------
__global__ __launch_bounds__(256) void wo_red_prenorm(const float* __restrict__ p, float* __restrict__ a_f,
                                                      bf16* __restrict__ an) {
  const int t = blockIdx.x, tid = threadIdx.x;
  const size_t base = (size_t)t * DD + tid * 8;
  float4 a0 = *(const float4*)(p + base),        a1 = *(const float4*)(p + base + 4);
  float4 b0 = *(const float4*)(p + DD2 + base),  b1 = *(const float4*)(p + DD2 + base + 4);
  float v[8] = {a0.x + b0.x, a0.y + b0.y, a0.z + b0.z, a0.w + b0.w,
                a1.x + b1.x, a1.y + b1.y, a1.z + b1.z, a1.w + b1.w};
  *(float4*)(a_f + base)     = make_float4(v[0], v[1], v[2], v[3]);
  *(float4*)(a_f + base + 4) = make_float4(v[4], v[5], v[6], v[7]);
  float ss = 0.f;
#pragma unroll
  for (int i = 0; i < 8; ++i) ss += v[i] * v[i];
#pragma unroll
  for (int off = 1; off < 64; off <<= 1) ss += __shfl_xor(ss, off, 64);
  __shared__ float red[4];
  if ((tid & 63) == 0) red[tid >> 6] = ss;
  __syncthreads();
  ss = red[0] + red[1] + red[2] + red[3];
  const float sc = rsqrtf(ss * (1.0f / DD) + 1.1920928955078125e-07f);
  bf16x8 o;
#pragma unroll
  for (int i = 0; i < 8; ++i) o[i] = (bf16)(v[i] * sc);
  *(bf16x8*)(an + base) = o;
}

__global__ __launch_bounds__(256) void proj_red(const float* __restrict__ p, const float* __restrict__ a_f,
                                                float* __restrict__ out) {
  const size_t base = ((size_t)blockIdx.x * 256 + threadIdx.x) * 8;
#pragma unroll
  for (int h = 0; h < 2; ++h) {
    size_t i = base + h * 4;
    float4 r = *(const float4*)(a_f + i);
    float4 u = *(const float4*)(p + i);
    float4 w = *(const float4*)(p + DD2 + i);
    float4 z = *(const float4*)(p + 2 * DD2 + i);
    *(float4*)(out + i) = make_float4(r.x + u.x + w.x + z.x, r.y + u.y + w.y + z.y,
                                      r.z + u.z + w.z + z.z, r.w + u.w + w.w + z.w);
  }
}

// ---------------- causal flash attention, no-max softmax ----------------
__global__ __launch_bounds__(256) void attn_k(const bf16* __restrict__ qg, const bf16* __restrict__ kg,
                                              const bf16* __restrict__ vtg, bf16* __restrict__ yg) {
  __shared__ alignas(16) bf16 Ks[32 * 128];
  __shared__ alignas(16) bf16 Vt[128 * 32];
  __shared__ alignas(16) bf16 Pl[4][16 * 32];
  const int h = blockIdx.y, qb = 31 - blockIdx.x;
  const int tid = threadIdx.x, lane = tid & 63, wid = tid >> 6;
  const int l15 = lane & 15, g = lane >> 4;
  const int qrow = qb * 64 + wid * 16;
  const float scale = 0.08838834764831845f;
  bf16x8 aQ[4];
  {
    const bf16* qp = qg + (size_t)(qrow + l15) * DD + h * 128 + g * 8;
#pragma unroll
    for (int kc = 0; kc < 4; ++kc) aQ[kc] = *(const bf16x8*)(qp + kc * 32);
  }
  f32x4 acc[8] = {};
  f32x4 l4 = {0.f, 0.f, 0.f, 0.f};
  const int nkt = qb * 2 + 2;
  for (int kt = 0; kt < nkt; ++kt) {
    const int kbase = kt * 32;
    __syncthreads();
#pragma unroll
    for (int r = 0; r < 2; ++r) {
      int e = tid + r * 256;
      int row = e >> 4, slot = e & 15;
      glds16(kg + (size_t)(kbase + row) * DD + h * 128 + ((slot ^ (row & 7)) * 8), Ks + e * 8);
    }
#pragma unroll
    for (int r = 0; r < 2; ++r) {
      int e = tid + r * 256;
      int d = e >> 2, slot = e & 3;
      glds16(vtg + (size_t)(h * 128 + d) * DD + kbase + ((slot ^ (d & 3)) * 8), Vt + e * 8);
    }
    __syncthreads();
    f32x4 S0 = {}, S1 = {};
#pragma unroll
    for (int kc = 0; kc < 4; ++kc) {
      int r0 = l15, r1 = 16 + l15;
      bf16x8 b0 = *(const bf16x8*)(Ks + r0 * 128 + (((kc * 4 + g) ^ (r0 & 7)) * 8));
      bf16x8 b1 = *(const bf16x8*)(Ks + r1 * 128 + (((kc * 4 + g) ^ (r1 & 7)) * 8));
      S0 = mfma16(aQ[kc], b0, S0);
      S1 = mfma16(aQ[kc], b1, S1);
    }
    const int k0i = kbase + l15, k1i = k0i + 16;
    f32x4 p0, p1;
#pragma unroll
    for (int j = 0; j < 4; ++j) {
      int q = qrow + g * 4 + j;
      p0[j] = (k0i <= q) ? __expf(S0[j] * scale) : 0.f;
      p1[j] = (k1i <= q) ? __expf(S1[j] * scale) : 0.f;
      l4[j] += p0[j] + p1[j];
    }
    const int c0 = (l15 >> 3) ^ g, c1 = (2 + (l15 >> 3)) ^ g, w7 = l15 & 7;
#pragma unroll
    for (int j = 0; j < 4; ++j) {
      Pl[wid][(g * 4 + j) * 32 + c0 * 8 + w7] = (bf16)p0[j];
      Pl[wid][(g * 4 + j) * 32 + c1 * 8 + w7] = (bf16)p1[j];
    }
    bf16x8 aP = *(const bf16x8*)(&Pl[wid][l15 * 32 + ((g ^ (l15 >> 2)) * 8)]);
#pragma unroll
    for (int dt = 0; dt < 8; ++dt) {
      int d = dt * 16 + l15;
      bf16x8 bV = *(const bf16x8*)(Vt + d * 32 + ((g ^ (d & 3)) * 8));
      acc[dt] = mfma16(aP, bV, acc[dt]);
    }
  }
#pragma unroll
  for (int off = 1; off < 16; off <<= 1)
#pragma unroll
    for (int j = 0; j < 4; ++j) l4[j] += __shfl_xor(l4[j], off, 64);
#pragma unroll
  for (int dt = 0; dt < 8; ++dt)
#pragma unroll
    for (int j = 0; j < 4; ++j) {
      int q = qrow + g * 4 + j;
      yg[(size_t)q * DD + h * 128 + dt * 16 + l15] = (bf16)(acc[dt][j] / l4[j]);
    }
}

extern "C" void kernel_launch(void* const* d_in, const int* in_sizes, int n_in,
                              void* d_out, int out_size, void* d_ws, size_t ws_size,
                              hipStream_t stream) {
  const float* x       = (const float*)d_in[0];
  const float* vi      = (const float*)d_in[1];
  const float* x0      = (const float*)d_in[2];
  const float* wq      = (const float*)d_in[3];
  const float* wk      = (const float*)d_in[4];
  const float* wv      = (const float*)d_in[5];
  const float* wo      = (const float*)d_in[6];
  const float* lamb    = (const float*)d_in[7];
  const float* lambdas = (const float*)d_in[8];
  const float* wfc     = (const float*)d_in[9];
  const float* wproj   = (const float*)d_in[10];
  float* out = (float*)d_out;

  (void)hipFuncSetAttribute(reinterpret_cast<const void*>(gemm9_qkv),
                            hipFuncAttributeMaxDynamicSharedMemorySize, G9_LDS);
  (void)hipFuncSetAttribute(reinterpret_cast<const void*>(gemm9_ep<2>),
                            hipFuncAttributeMaxDynamicSharedMemorySize, G9_LDS);
  (void)hipFuncSetAttribute(reinterpret_cast<const void*>(gemm9_ep<3>),
                            hipFuncAttributeMaxDynamicSharedMemorySize, G9_LDS);

  char* wsb = (char*)d_ws;
  size_t off = 0;
  auto alloc = [&](size_t bytes) { void* p = wsb + off; off = (off + bytes + 255) & ~(size_t)255; return p; };
  bf16* wq_b  = (bf16*)alloc(DD2 * 2);
  bf16* wk_b  = (bf16*)alloc(DD2 * 2);
  bf16* wv_b  = (bf16*)alloc(DD2 * 2);
  bf16* wo_b  = (bf16*)alloc(DD2 * 2);
  bf16* wfc_b = (bf16*)alloc(DD2 * 8);
  bf16* wpj_b = (bf16*)alloc(DD2 * 8);
  // region xn..an (48MB contiguous) doubles as split-K f32 partials (up to 3 x 16MB)
  bf16* xn_b  = (bf16*)alloc(DD2 * 2);
  bf16* q_b   = (bf16*)alloc(DD2 * 2);
  bf16* k_b   = (bf16*)alloc(DD2 * 2);
  bf16* v_b   = (bf16*)alloc(DD2 * 2);
  bf16* y_b   = (bf16*)alloc(DD2 * 2);
  bf16* an_b  = (bf16*)alloc(DD2 * 2);
  float* part = (float*)xn_b;   // wo uses 2 partials (xn..v); proj uses 3 (xn..an)
  float* a_f  = (float*)alloc(DD2 * 4);
  bf16* h_b   = (bf16*)alloc(DD2 * 8);
  bf16* vt_b  = h_b;            // alias: vt dead before fc writes h

  cvt_all<<<24576, 256, 0, stream>>>(wq, wk, wv, wo, wfc, wproj, (bf16*)wsb);
  prenorm_k<true><<<2048, 256, 0, stream>>>(x, x0, lambdas, xn_b);
  gemm9_qkv<<<dim3(8, 8, 3), 512, G9_LDS, stream>>>(xn_b, wq_b, wk_b, wv_b, q_b, k_b, v_b, vi, lamb);
  rope_k<<<16384, 256, 0, stream>>>(q_b, k_b);
  vt_k<<<dim3(128, 16), 256, 0, stream>>>(v_b, vt_b);
  attn_k<<<dim3(32, 16), 256, 0, stream>>>(q_b, k_b, vt_b, y_b);
  gemm9_ep<2><<<dim3(8, 8, 2), 512, G9_LDS, stream>>>(y_b, wo_b, (void*)part, DD, DD, 1024, DD);
  wo_red_prenorm<<<2048, 256, 0, stream>>>(part, a_f, an_b);
  gemm9_ep<3><<<dim3(32, 8, 1), 512, G9_LDS, stream>>>(an_b, wfc_b, (void*)h_b, 4 * DD, DD, DD, DD);
  gemm9_ep<2><<<dim3(8, 8, 3), 512, G9_LDS, stream>>>(h_b, wpj_b, (void*)part, DD, 4 * DD, 2752, 4 * DD);
  proj_red<<<2048, 256, 0, stream>>>(part, a_f, out);
}

// Round 5
// 386.784 us; speedup vs baseline: 1.8228x; 1.0528x over previous
//
#include <hip/hip_runtime.h>
#include <hip/hip_bf16.h>

typedef __bf16 bf16;
typedef __bf16 bf16x8 __attribute__((ext_vector_type(8)));
typedef float f32x4 __attribute__((ext_vector_type(4)));
typedef unsigned int u32x4 __attribute__((ext_vector_type(4)));

#define DD 2048
#define DD2 4194304ull
#define G9_LDS 131072   // 2 buffers x (A[256][64] + B[256][64]) bf16

__device__ __forceinline__ void glds16(const void* g, void* l) {
  __builtin_amdgcn_global_load_lds((const __attribute__((address_space(1))) void*)g,
                                   (__attribute__((address_space(3))) void*)l, 16, 0, 0);
}

__device__ __forceinline__ f32x4 mfma16(bf16x8 a, bf16x8 b, f32x4 c) {
  return __builtin_amdgcn_mfma_f32_16x16x32_bf16(a, b, c, 0, 0, 0);
}

__device__ __forceinline__ unsigned pk2(float lo, float hi) {
  unsigned short a = __builtin_bit_cast(unsigned short, (bf16)lo);
  unsigned short b = __builtin_bit_cast(unsigned short, (bf16)hi);
  return (unsigned)a | ((unsigned)b << 16);
}

// ---------------- fused fp32 -> bf16 convert of all 6 weights ----------------
__global__ __launch_bounds__(256) void cvt_all(const float* __restrict__ s0, const float* __restrict__ s1,
                                               const float* __restrict__ s2, const float* __restrict__ s3,
                                               const float* __restrict__ s4, const float* __restrict__ s5,
                                               bf16* __restrict__ dbase) {
  const int b = blockIdx.x;
  const float* src; bf16* dst; int lb;
  if (b < 8192)       { int r = b >> 11; src = (r == 0) ? s0 : (r == 1) ? s1 : (r == 2) ? s2 : s3;
                        dst = dbase + (size_t)r * DD2; lb = b & 2047; }
  else if (b < 16384) { src = s4; dst = dbase + 4 * DD2; lb = b - 8192; }
  else                { src = s5; dst = dbase + 8 * DD2; lb = b - 16384; }
  size_t i = ((size_t)lb * 256 + threadIdx.x) * 8;
  float4 a = *(const float4*)(src + i);
  float4 c = *(const float4*)(src + i + 4);
  bf16x8 o;
  o[0] = (bf16)a.x; o[1] = (bf16)a.y; o[2] = (bf16)a.z; o[3] = (bf16)a.w;
  o[4] = (bf16)c.x; o[5] = (bf16)c.y; o[6] = (bf16)c.z; o[7] = (bf16)c.w;
  *(bf16x8*)(dst + i) = o;
}

// ---------------- RMSNorm (optionally blended), fp32 in -> bf16 out ----------------
template<bool BLEND>
__global__ __launch_bounds__(256) void prenorm_k(const float* __restrict__ x, const float* __restrict__ x0,
                                                 const float* __restrict__ lambdas, bf16* __restrict__ out) {
  const int t = blockIdx.x, tid = threadIdx.x;
  const float4* xr = (const float4*)(x + (size_t)t * DD);
  float4 a0 = xr[2 * tid], a1 = xr[2 * tid + 1];
  float v[8] = {a0.x, a0.y, a0.z, a0.w, a1.x, a1.y, a1.z, a1.w};
  if (BLEND) {
    const float l0 = lambdas[0], l1 = lambdas[1];
    const float4* yr = (const float4*)(x0 + (size_t)t * DD);
    float4 b0 = yr[2 * tid], b1 = yr[2 * tid + 1];
    float w[8] = {b0.x, b0.y, b0.z, b0.w, b1.x, b1.y, b1.z, b1.w};
#pragma unroll
    for (int i = 0; i < 8; ++i) v[i] = l0 * v[i] + l1 * w[i];
  }
  float ss = 0.f;
#pragma unroll
  for (int i = 0; i < 8; ++i) ss += v[i] * v[i];
#pragma unroll
  for (int off = 1; off < 64; off <<= 1) ss += __shfl_xor(ss, off, 64);
  __shared__ float red[4];
  const int wid = tid >> 6;
  if ((tid & 63) == 0) red[wid] = ss;
  __syncthreads();
  ss = red[0] + red[1] + red[2] + red[3];
  const float sc = rsqrtf(ss * (1.0f / DD) + 1.1920928955078125e-07f);
  bf16x8 o;
#pragma unroll
  for (int i = 0; i < 8; ++i) o[i] = (bf16)(v[i] * sc);
  *(bf16x8*)(out + (size_t)t * DD + tid * 8) = o;
}

// ---------------- per-(t,h) RMSNorm + rotary, in-place on bf16 q/k ----------------
__global__ __launch_bounds__(256) void rope_k(bf16* __restrict__ qg, bf16* __restrict__ kg) {
  const int tid = threadIdx.x, lane = tid & 63, wid = tid >> 6;
  const int p = blockIdx.x * 4 + wid;          // [arr(2)][t(2048)][h(16)]
  bf16* base = ((p >> 15) ? kg : qg);
  const int t = (p >> 4) & 2047, hh = p & 15;
  base += (size_t)t * DD + hh * 128;
  float x1 = (float)base[lane], x2 = (float)base[lane + 64];
  float ss = x1 * x1 + x2 * x2;
#pragma unroll
  for (int off = 1; off < 64; off <<= 1) ss += __shfl_xor(ss, off, 64);
  const float sc = rsqrtf(ss * (1.0f / 128.0f) + 1.1920928955078125e-07f);
  x1 *= sc; x2 *= sc;
  const float fr = (float)t * exp2f((float)lane * (-13.287712379549449f / 64.0f));
  const float s = sinf(fr), c = cosf(fr);
  base[lane]      = (bf16)(x1 * c + x2 * s);
  base[lane + 64] = (bf16)(-x1 * s + x2 * c);
}

// ---------------- V transpose: v[t][2048] -> vt[d2][t] ----------------
__global__ __launch_bounds__(256) void vt_k(const bf16* __restrict__ v, bf16* __restrict__ vt) {
  __shared__ alignas(16) bf16 tile[16 * 128];
  const int tb = blockIdx.x, hb = blockIdx.y, tid = threadIdx.x;
  glds16(v + (size_t)(tb * 16 + (tid >> 4)) * DD + hb * 128 + (tid & 15) * 8, tile + tid * 8);
  __syncthreads();
  const int d_l = tid & 127, tc = tid >> 7;
  bf16x8 o;
#pragma unroll
  for (int i = 0; i < 8; ++i) o[i] = tile[(tc * 8 + i) * 128 + d_l];
  *(bf16x8*)(vt + (size_t)(hb * 128 + d_l) * DD + tb * 16 + tc * 8) = o;
}

// ================ 256x256-tile, 8-wave, phase-interleaved GEMM ================
// 8 waves (2M x 4N). Phase = [dsr(cur); stage->other; counted vmcnt; barrier; MFMA].
// Stage units in consumption order U0=Ah0, U2=Bh0, U3=Bh1, U1=Ah1; vmcnt(4) steady.
__device__ __forceinline__ void g9_stageA(const bf16* A, int Kstride, int row0, int k0,
                                          bf16* buf, int hm, int tid) {
#pragma unroll
  for (int i = 0; i < 2; ++i) {
    int e = tid + i * 512;                 // [0,1024): prl = e>>3, slot = e&7
    int prl = e >> 3, slot = e & 7;
    int wm = prl >> 6, r63 = prl & 63;
    glds16(A + (size_t)(row0 + wm * 128 + hm * 64 + r63) * Kstride + k0 + ((slot ^ (prl & 7)) * 8),
           buf + hm * 8192 + e * 8);
  }
}
__device__ __forceinline__ void g9_stageB(const bf16* B, int Kstride, int col0, int k0,
                                          bf16* buf, int hn, int tid) {
#pragma unroll
  for (int i = 0; i < 2; ++i) {
    int e = tid + i * 512;
    int pbl = e >> 3, slot = e & 7;
    int wn = pbl >> 5, q = pbl & 31;
    glds16(B + (size_t)(col0 + wn * 64 + hn * 32 + q) * Kstride + k0 + ((slot ^ (pbl & 7)) * 8),
           buf + 16384 + hn * 8192 + e * 8);
  }
}

__device__ __forceinline__ void gemm9_core(const bf16* __restrict__ A, const bf16* __restrict__ B,
                                           int Kstride, int Klen, int row0, int col0,
                                           bf16* smem, f32x4 (&acc)[8][4]) {
  const int tid = threadIdx.x, lane = tid & 63, wid = tid >> 6;
  const int wm = wid >> 2, wn = wid & 3;
  const int l15 = lane & 15, g = lane >> 4;
  const int sw = l15 & 7;
  const int NT = Klen >> 6;
  // prologue: tile 0 in consumption order U0,U2,U3,U1
  g9_stageA(A, Kstride, row0, 0, smem, 0, tid);
  g9_stageB(B, Kstride, col0, 0, smem, 0, tid);
  g9_stageB(B, Kstride, col0, 0, smem, 1, tid);
  g9_stageA(A, Kstride, row0, 0, smem, 1, tid);
  asm volatile("s_waitcnt vmcnt(4)" ::: "memory");
  __builtin_amdgcn_s_barrier();

  bf16x8 a[4][2], b0[2][2], b1[2][2];
  for (int t = 0; t < NT; ++t) {
    bf16* cb = smem + (t & 1) * 32768;
    bf16* sb = smem + ((t + 1) & 1) * 32768;
    const int ks0 = (t + 1) << 6;
    const bool st = (t + 1) < NT;
    // ---- PH1: dsr a(hm0), b0(hn0); stage U0'; wait U3; bar; MFMA Q(0,0)
#pragma unroll
    for (int mm = 0; mm < 4; ++mm)
#pragma unroll
      for (int ks = 0; ks < 2; ++ks)
        a[mm][ks] = *(const bf16x8*)(cb + (wm * 64 + mm * 16 + l15) * 64 + (((ks * 4 + g) ^ sw) * 8));
#pragma unroll
    for (int nn = 0; nn < 2; ++nn)
#pragma unroll
      for (int ks = 0; ks < 2; ++ks)
        b0[nn][ks] = *(const bf16x8*)(cb + 16384 + (wn * 32 + nn * 16 + l15) * 64 + (((ks * 4 + g) ^ sw) * 8));
    if (st) g9_stageA(A, Kstride, row0, ks0, sb, 0, tid);
    if (st) { asm volatile("s_waitcnt vmcnt(4)" ::: "memory"); }
    else    { asm volatile("s_waitcnt vmcnt(2)" ::: "memory"); }
    __builtin_amdgcn_s_barrier();
    __builtin_amdgcn_s_setprio(1);
#pragma unroll
    for (int mm = 0; mm < 4; ++mm)
#pragma unroll
      for (int nn = 0; nn < 2; ++nn)
#pragma unroll
        for (int ks = 0; ks < 2; ++ks)
          acc[mm][nn] = mfma16(a[mm][ks], b0[nn][ks], acc[mm][nn]);
    __builtin_amdgcn_s_setprio(0);
    // ---- PH2: dsr b1(hn1); stage U2'; wait U1; bar; MFMA Q(0,1)
#pragma unroll
    for (int nn = 0; nn < 2; ++nn)
#pragma unroll
      for (int ks = 0; ks < 2; ++ks)
        b1[nn][ks] = *(const bf16x8*)(cb + 16384 + 8192 + (wn * 32 + nn * 16 + l15) * 64 + (((ks * 4 + g) ^ sw) * 8));
    if (st) g9_stageB(B, Kstride, col0, ks0, sb, 0, tid);
    if (st) { asm volatile("s_waitcnt vmcnt(4)" ::: "memory"); }
    else    { asm volatile("s_waitcnt vmcnt(0)" ::: "memory"); }
    __builtin_amdgcn_s_barrier();
    __builtin_amdgcn_s_setprio(1);
#pragma unroll
    for (int mm = 0; mm < 4; ++mm)
#pragma unroll
      for (int nn = 0; nn < 2; ++nn)
#pragma unroll
        for (int ks = 0; ks < 2; ++ks)
          acc[mm][2 + nn] = mfma16(a[mm][ks], b1[nn][ks], acc[mm][2 + nn]);
    __builtin_amdgcn_s_setprio(0);
    // ---- PH3: dsr a(hm1); stage U3'; bar; MFMA Q(1,0)
#pragma unroll
    for (int mm = 0; mm < 4; ++mm)
#pragma unroll
      for (int ks = 0; ks < 2; ++ks)
        a[mm][ks] = *(const bf16x8*)(cb + 8192 + (wm * 64 + mm * 16 + l15) * 64 + (((ks * 4 + g) ^ sw) * 8));
    if (st) g9_stageB(B, Kstride, col0, ks0, sb, 1, tid);
    __builtin_amdgcn_s_barrier();
    __builtin_amdgcn_s_setprio(1);
#pragma unroll
    for (int mm = 0; mm < 4; ++mm)
#pragma unroll
      for (int nn = 0; nn < 2; ++nn)
#pragma unroll
        for (int ks = 0; ks < 2; ++ks)
          acc[4 + mm][nn] = mfma16(a[mm][ks], b0[nn][ks], acc[4 + mm][nn]);
    __builtin_amdgcn_s_setprio(0);
    // ---- PH4: stage U1'; wait U0',U2' (for next PH1 dsr); bar; MFMA Q(1,1)
    if (st) { g9_stageA(A, Kstride, row0, ks0, sb, 1, tid);
              asm volatile("s_waitcnt vmcnt(4)" ::: "memory"); }
    __builtin_amdgcn_s_barrier();
    __builtin_amdgcn_s_setprio(1);
#pragma unroll
    for (int mm = 0; mm < 4; ++mm)
#pragma unroll
      for (int nn = 0; nn < 2; ++nn)
#pragma unroll
        for (int ks = 0; ks < 2; ++ks)
          acc[4 + mm][2 + nn] = mfma16(a[mm][ks], b1[nn][ks], acc[4 + mm][2 + nn]);
    __builtin_amdgcn_s_setprio(0);
  }
}

// D layout: col=lane&15, row=(lane>>4)*4+j; acc[m][n]: hm=m>>2, mm=m&3, hn=n>>1, nn=n&1
#define GEMM9_EPI(STMT)                                                        \
  { const int lane_ = threadIdx.x & 63, wid_ = threadIdx.x >> 6;               \
    const int l15_ = lane_ & 15, g_ = lane_ >> 4;                              \
    const int wm_ = wid_ >> 2, wn_ = wid_ & 3;                                 \
    _Pragma("unroll") for (int m = 0; m < 8; ++m)                              \
    _Pragma("unroll") for (int n = 0; n < 4; ++n)                              \
    _Pragma("unroll") for (int j = 0; j < 4; ++j) {                            \
      int grow = row0 + wm_ * 128 + (m >> 2) * 64 + (m & 3) * 16 + g_ * 4 + j; \
      int gcol = col0 + wn_ * 64 + (n >> 1) * 32 + (n & 1) * 16 + l15_;        \
      float vacc = acc[m][n][j];                                               \
      STMT; } }

__global__ __launch_bounds__(512, 1) void gemm9_qkv(const bf16* __restrict__ A,
    const bf16* __restrict__ Wq, const bf16* __restrict__ Wk, const bf16* __restrict__ Wv,
    bf16* __restrict__ oq, bf16* __restrict__ ok, bf16* __restrict__ ov,
    const float* __restrict__ vi, const float* __restrict__ lambp) {
  extern __shared__ bf16 smem9[];
  const int z = blockIdx.z;
  const bf16* B = (z == 0) ? Wq : (z == 1) ? Wk : Wv;
  bf16* out = (z == 0) ? oq : (z == 1) ? ok : ov;
  const int row0 = blockIdx.y * 256, col0 = blockIdx.x * 256;
  f32x4 acc[8][4] = {};
  gemm9_core(A, B, DD, DD, row0, col0, smem9, acc);
  if (z < 2) {
    GEMM9_EPI( out[(size_t)grow * DD + gcol] = (bf16)vacc; )
  } else {
    const float lam = *lambp;
    GEMM9_EPI( out[(size_t)grow * DD + gcol] =
                 (bf16)((1.0f - lam) * vacc + lam * vi[(size_t)grow * DD + gcol]); )
  }
}

// split-K partial GEMM: z < zsw -> o1 + z*DD2 ; else o2 + (z-zsw)*DD2
__global__ __launch_bounds__(512, 1) void gemm9_part(const bf16* __restrict__ A, const bf16* __restrict__ B,
                                                     float* __restrict__ o1, float* __restrict__ o2,
                                                     int zsw, int N, int Kstride, int Klen) {
  extern __shared__ bf16 smem9[];
  const int row0 = blockIdx.y * 256, col0 = blockIdx.x * 256;
  const int z = blockIdx.z, kofs = z * Klen;
  float* out = (z < zsw) ? (o1 + (size_t)z * DD2) : (o2 + (size_t)(z - zsw) * DD2);
  f32x4 acc[8][4] = {};
  gemm9_core(A + kofs, B + kofs, Kstride, Klen, row0, col0, smem9, acc);
  GEMM9_EPI( out[(size_t)grow * N + gcol] = vacc; )
}

__global__ __launch_bounds__(512, 1) void gemm9_relu(const bf16* __restrict__ A, const bf16* __restrict__ B,
                                                     bf16* __restrict__ out, int N, int Kstride, int Klen) {
  extern __shared__ bf16 smem9[];
  const int row0 = blockIdx.y * 256, col0 = blockIdx.x * 256;
  f32x4 acc[8][4] = {};
  gemm9_core(A, B, Kstride, Klen, row0, col0, smem9, acc);
  GEMM9_EPI( float r = fmaxf(vacc, 0.f); out[(size_t)grow * N + gcol] = (bf16)(r * r); )
}

// ---------------- split-K reduces ----------------
__global__ __launch_bounds__(256) void wo_red_prenorm(const float* __restrict__ pa, const float* __restrict__ pb,
                                                      float* __restrict__ a_f, bf16* __restrict__ an) {
  const int t = blockIdx.x, tid = threadIdx.x;
  const size_t base = (size_t)t * DD + tid * 8;
  float v[8];
#pragma unroll
  for (int h = 0; h < 2; ++h) {
    size_t i = base + h * 4;
    float4 r0 = *(const float4*)(pa + i);
    float4 r1 = *(const float4*)(pa + DD2 + i);
    float4 r2 = *(const float4*)(pb + i);
    float4 r3 = *(const float4*)(pb + DD2 + i);
    v[h*4+0] = r0.x + r1.x + r2.x + r3.x;
    v[h*4+1] = r0.y + r1.y + r2.y + r3.y;
    v[h*4+2] = r0.z + r1.z + r2.z + r3.z;
    v[h*4+3] = r0.w + r1.w + r2.w + r3.w;
  }
  *(float4*)(a_f + base)     = make_float4(v[0], v[1], v[2], v[3]);
  *(float4*)(a_f + base + 4) = make_float4(v[4], v[5], v[6], v[7]);
  float ss = 0.f;
#pragma unroll
  for (int i = 0; i < 8; ++i) ss += v[i] * v[i];
#pragma unroll
  for (int off = 1; off < 64; off <<= 1) ss += __shfl_xor(ss, off, 64);
  __shared__ float red[4];
  if ((tid & 63) == 0) red[tid >> 6] = ss;
  __syncthreads();
  ss = red[0] + red[1] + red[2] + red[3];
  const float sc = rsqrtf(ss * (1.0f / DD) + 1.1920928955078125e-07f);
  bf16x8 o;
#pragma unroll
  for (int i = 0; i < 8; ++i) o[i] = (bf16)(v[i] * sc);
  *(bf16x8*)(an + base) = o;
}

__global__ __launch_bounds__(256) void proj_red(const float* __restrict__ pa, const float* __restrict__ pw,
                                                const float* __restrict__ a_f, float* __restrict__ out) {
  const size_t base = ((size_t)blockIdx.x * 256 + threadIdx.x) * 8;
#pragma unroll
  for (int h = 0; h < 2; ++h) {
    size_t i = base + h * 4;
    float4 r = *(const float4*)(a_f + i);
    float4 u = *(const float4*)(pa + i);
    float4 w = *(const float4*)(pa + DD2 + i);
    float4 z = *(const float4*)(pa + 2 * DD2 + i);
    float4 y = *(const float4*)(pw + i);
    *(float4*)(out + i) = make_float4(r.x + u.x + w.x + z.x + y.x,
                                      r.y + u.y + w.y + z.y + y.y,
                                      r.z + u.z + w.z + z.z + y.z,
                                      r.w + u.w + w.w + z.w + y.w);
  }
}

// ---------------- causal flash attention ----------------
// Swapped QK^T (lane holds S[q=l15][k]), no-max softmax (q,k RMS-normed: |s|<=11.32),
// P->A-frag via cvt-pack + 8 shfl (no LDS round trip), triple-buffered K/V staging
// with one barrier + counted vmcnt per tile.
__device__ __forceinline__ void att_stageK(const bf16* kg, int h, int kt, bf16* dst, int tid) {
#pragma unroll
  for (int r = 0; r < 2; ++r) {
    int e = tid + r * 256, row = e >> 4, slot = e & 15;
    glds16(kg + (size_t)(kt * 32 + row) * DD + h * 128 + ((slot ^ (row & 7)) * 8), dst + e * 8);
  }
}
__device__ __forceinline__ void att_stageV(const bf16* vtg, int h, int kt, bf16* dst, int tid) {
#pragma unroll
  for (int r = 0; r < 2; ++r) {
    int e = tid + r * 256, d = e >> 2, slot = e & 3;
    glds16(vtg + (size_t)(h * 128 + d) * DD + kt * 32 + ((slot ^ ((d >> 1) & 3)) * 8), dst + e * 8);
  }
}

__global__ __launch_bounds__(256) void attn_k(const bf16* __restrict__ qg, const bf16* __restrict__ kg,
                                              const bf16* __restrict__ vtg, bf16* __restrict__ yg) {
  __shared__ alignas(16) bf16 Ks[3][32 * 128];
  __shared__ alignas(16) bf16 Vt[3][128 * 32];
  const int h = blockIdx.y, qb = 31 - blockIdx.x;
  const int tid = threadIdx.x, lane = tid & 63, wid = tid >> 6;
  const int l15 = lane & 15, g = lane >> 4, swl = l15 & 7;
  const int qrow = qb * 64 + wid * 16;
  const float scale = 0.08838834764831845f;   // 1/sqrt(128)
  bf16x8 aQ[4];
  {
    const bf16* qp = qg + (size_t)(qrow + l15) * DD + h * 128 + g * 8;
#pragma unroll
    for (int kc = 0; kc < 4; ++kc) aQ[kc] = *(const bf16x8*)(qp + kc * 32);
  }
  f32x4 acc[8] = {};
  float lsum = 0.f;
  const int nkt = qb * 2 + 2;                 // always >= 2
  att_stageK(kg, h, 0, Ks[0], tid);
  att_stageV(vtg, h, 0, Vt[0], tid);
  att_stageK(kg, h, 1, Ks[1], tid);
  att_stageV(vtg, h, 1, Vt[1], tid);
  asm volatile("s_waitcnt vmcnt(4)" ::: "memory");   // tile0 (+Q) landed
  __builtin_amdgcn_s_barrier();
  int cur = 0;
  for (int kt = 0; kt < nkt; ++kt) {
    const int kbase = kt * 32;
    const int nb = (cur >= 1) ? cur - 1 : 2;  // (cur+2)%3
    // K fragments (A-operand: lane row = k)
    bf16x8 kf0[4], kf1[4];
#pragma unroll
    for (int kc = 0; kc < 4; ++kc) {
      kf0[kc] = *(const bf16x8*)(Ks[cur] + l15 * 128 + (((kc * 4 + g) ^ swl) * 8));
      kf1[kc] = *(const bf16x8*)(Ks[cur] + (16 + l15) * 128 + (((kc * 4 + g) ^ swl) * 8));
    }
    if (kt + 2 < nkt) { att_stageK(kg, h, kt + 2, Ks[nb], tid);
                        att_stageV(vtg, h, kt + 2, Vt[nb], tid); }
    // S^T = K * Q^T : lane holds S[q=l15][k=kbase+4g+j (+16)]
    f32x4 S0 = {}, S1 = {};
#pragma unroll
    for (int kc = 0; kc < 4; ++kc) {
      S0 = mfma16(kf0[kc], aQ[kc], S0);
      S1 = mfma16(kf1[kc], aQ[kc], S1);
    }
    const int q = qrow + l15;
    float p0[4], p1[4];
#pragma unroll
    for (int j = 0; j < 4; ++j) {
      int k0 = kbase + 4 * g + j;
      p0[j] = (k0 <= q) ? __expf(S0[j] * scale) : 0.f;
      p1[j] = (k0 + 16 <= q) ? __expf(S1[j] * scale) : 0.f;
      lsum += p0[j] + p1[j];
    }
    // pack to bf16 pairs, redistribute to PV A-frag layout (lane needs k = 8g..8g+7 for q=l15)
    unsigned w0 = pk2(p0[0], p0[1]), w1 = pk2(p0[2], p0[3]);
    unsigned w2 = pk2(p1[0], p1[1]), w3 = pk2(p1[2], p1[3]);
    const int s0l = (g & 1) * 32 + l15, s1l = s0l + 16;
    const bool hi = g >= 2;
    unsigned t00 = __shfl(w0, s0l, 64), t10 = __shfl(w1, s0l, 64);
    unsigned t01 = __shfl(w0, s1l, 64), t11 = __shfl(w1, s1l, 64);
    unsigned u00 = __shfl(w2, s0l, 64), u10 = __shfl(w3, s0l, 64);
    unsigned u01 = __shfl(w2, s1l, 64), u11 = __shfl(w3, s1l, 64);
    u32x4 av = { hi ? u00 : t00, hi ? u10 : t10, hi ? u01 : t01, hi ? u11 : t11 };
    bf16x8 aP = __builtin_bit_cast(bf16x8, av);
#pragma unroll
    for (int dt = 0; dt < 8; ++dt) {
      int d = dt * 16 + l15;
      bf16x8 bV = *(const bf16x8*)(Vt[cur] + d * 32 + ((g ^ ((d >> 1) & 3)) * 8));
      acc[dt] = mfma16(aP, bV, acc[dt]);
    }
    if (kt + 1 < nkt) {
      if (kt + 2 < nkt) { asm volatile("s_waitcnt vmcnt(4)" ::: "memory"); }
      else              { asm volatile("s_waitcnt vmcnt(0)" ::: "memory"); }
      __builtin_amdgcn_s_barrier();
    }
    cur = (cur == 2) ? 0 : cur + 1;
  }
  lsum += __shfl_xor(lsum, 16, 64);
  lsum += __shfl_xor(lsum, 32, 64);
  f32x4 linv;
#pragma unroll
  for (int j = 0; j < 4; ++j) linv[j] = 1.0f / __shfl(lsum, 4 * g + j, 64);
#pragma unroll
  for (int dt = 0; dt < 8; ++dt)
#pragma unroll
    for (int j = 0; j < 4; ++j) {
      int q = qrow + 4 * g + j;
      yg[(size_t)q * DD + h * 128 + dt * 16 + l15] = (bf16)(acc[dt][j] * linv[j]);
    }
}

extern "C" void kernel_launch(void* const* d_in, const int* in_sizes, int n_in,
                              void* d_out, int out_size, void* d_ws, size_t ws_size,
                              hipStream_t stream) {
  const float* x       = (const float*)d_in[0];
  const float* vi      = (const float*)d_in[1];
  const float* x0      = (const float*)d_in[2];
  const float* wq      = (const float*)d_in[3];
  const float* wk      = (const float*)d_in[4];
  const float* wv      = (const float*)d_in[5];
  const float* wo      = (const float*)d_in[6];
  const float* lamb    = (const float*)d_in[7];
  const float* lambdas = (const float*)d_in[8];
  const float* wfc     = (const float*)d_in[9];
  const float* wproj   = (const float*)d_in[10];
  float* out = (float*)d_out;

  (void)hipFuncSetAttribute(reinterpret_cast<const void*>(gemm9_qkv),
                            hipFuncAttributeMaxDynamicSharedMemorySize, G9_LDS);
  (void)hipFuncSetAttribute(reinterpret_cast<const void*>(gemm9_part),
                            hipFuncAttributeMaxDynamicSharedMemorySize, G9_LDS);
  (void)hipFuncSetAttribute(reinterpret_cast<const void*>(gemm9_relu),
                            hipFuncAttributeMaxDynamicSharedMemorySize, G9_LDS);

  char* wsb = (char*)d_ws;
  size_t off = 0;
  auto alloc = [&](size_t bytes) { void* p = wsb + off; off = (off + bytes + 255) & ~(size_t)255; return p; };
  bf16* wq_b  = (bf16*)alloc(DD2 * 2);
  bf16* wk_b  = (bf16*)alloc(DD2 * 2);
  bf16* wv_b  = (bf16*)alloc(DD2 * 2);
  bf16* wo_b  = (bf16*)alloc(DD2 * 2);
  bf16* wfc_b = (bf16*)alloc(DD2 * 8);   // dead after fc -> proj 4th partial
  bf16* wpj_b = (bf16*)alloc(DD2 * 8);
  // xn..an: 48MB contiguous; doubles as split-K f32 partials when dead
  bf16* xn_b  = (bf16*)alloc(DD2 * 2);
  bf16* q_b   = (bf16*)alloc(DD2 * 2);
  bf16* k_b   = (bf16*)alloc(DD2 * 2);
  bf16* v_b   = (bf16*)alloc(DD2 * 2);
  bf16* y_b   = (bf16*)alloc(DD2 * 2);
  bf16* an_b  = (bf16*)alloc(DD2 * 2);
  float* partA = (float*)xn_b;           // wo: splits 0,1 (xn..v) ; proj: splits 0..2 (xn..an)
  float* a_f  = (float*)alloc(DD2 * 4);
  bf16* h_b   = (bf16*)alloc(DD2 * 8);
  bf16* vt_b  = h_b;                     // vt dead before wo partials / fc output reuse h_b
  float* partB = (float*)h_b;            // wo: splits 2,3

  cvt_all<<<24576, 256, 0, stream>>>(wq, wk, wv, wo, wfc, wproj, (bf16*)wsb);
  prenorm_k<true><<<2048, 256, 0, stream>>>(x, x0, lambdas, xn_b);
  gemm9_qkv<<<dim3(8, 8, 3), 512, G9_LDS, stream>>>(xn_b, wq_b, wk_b, wv_b, q_b, k_b, v_b, vi, lamb);
  rope_k<<<16384, 256, 0, stream>>>(q_b, k_b);
  vt_k<<<dim3(128, 16), 256, 0, stream>>>(v_b, vt_b);
  attn_k<<<dim3(32, 16), 256, 0, stream>>>(q_b, k_b, vt_b, y_b);
  gemm9_part<<<dim3(8, 8, 4), 512, G9_LDS, stream>>>(y_b, wo_b, partA, partB, 2, DD, DD, 512);
  wo_red_prenorm<<<2048, 256, 0, stream>>>(partA, partB, a_f, an_b);
  gemm9_relu<<<dim3(32, 8), 512, G9_LDS, stream>>>(an_b, wfc_b, h_b, 4 * DD, DD, DD);
  gemm9_part<<<dim3(8, 8, 4), 512, G9_LDS, stream>>>(h_b, wpj_b, partA, (float*)wfc_b, 3, DD, 4 * DD, 2048);
  proj_red<<<2048, 256, 0, stream>>>(partA, (float*)wfc_b, a_f, out);
}

// Round 6
// 386.037 us; speedup vs baseline: 1.8263x; 1.0019x over previous
//
#include <hip/hip_runtime.h>
#include <hip/hip_bf16.h>

typedef __bf16 bf16;
typedef __bf16 bf16x8 __attribute__((ext_vector_type(8)));
typedef float f32x4 __attribute__((ext_vector_type(4)));
typedef unsigned int u32x4 __attribute__((ext_vector_type(4)));

#define DD 2048
#define DD2 4194304ull
#define G9_LDS 131072   // 2 buffers x (A[256][64] + B[256][64]) bf16

__device__ __forceinline__ void glds16(const void* g, void* l) {
  __builtin_amdgcn_global_load_lds((const __attribute__((address_space(1))) void*)g,
                                   (__attribute__((address_space(3))) void*)l, 16, 0, 0);
}

__device__ __forceinline__ f32x4 mfma16(bf16x8 a, bf16x8 b, f32x4 c) {
  return __builtin_amdgcn_mfma_f32_16x16x32_bf16(a, b, c, 0, 0, 0);
}

__device__ __forceinline__ unsigned pk2(float lo, float hi) {
  unsigned short a = __builtin_bit_cast(unsigned short, (bf16)lo);
  unsigned short b = __builtin_bit_cast(unsigned short, (bf16)hi);
  return (unsigned)a | ((unsigned)b << 16);
}

// ---------------- fp32 -> bf16 convert, grid-stride, 16 elems/thread/iter ----------------
// dst is 4 contiguous segments of (1<<seglog) elems from s0..s3.
__global__ __launch_bounds__(256) void cvt_seg(const float* __restrict__ s0, const float* __restrict__ s1,
                                               const float* __restrict__ s2, const float* __restrict__ s3,
                                               bf16* __restrict__ dst, int seglog, size_t total) {
  size_t i = ((size_t)blockIdx.x * 256 + threadIdx.x) * 16;
  const size_t stride = (size_t)gridDim.x * 256 * 16;
  for (; i < total; i += stride) {
    int seg = (int)(i >> seglog);
    const float* src = (seg == 0) ? s0 : (seg == 1) ? s1 : (seg == 2) ? s2 : s3;
    size_t loc = i - ((size_t)seg << seglog);
    float4 a0 = *(const float4*)(src + loc);
    float4 a1 = *(const float4*)(src + loc + 4);
    float4 a2 = *(const float4*)(src + loc + 8);
    float4 a3 = *(const float4*)(src + loc + 12);
    bf16x8 o0, o1;
    o0[0] = (bf16)a0.x; o0[1] = (bf16)a0.y; o0[2] = (bf16)a0.z; o0[3] = (bf16)a0.w;
    o0[4] = (bf16)a1.x; o0[5] = (bf16)a1.y; o0[6] = (bf16)a1.z; o0[7] = (bf16)a1.w;
    o1[0] = (bf16)a2.x; o1[1] = (bf16)a2.y; o1[2] = (bf16)a2.z; o1[3] = (bf16)a2.w;
    o1[4] = (bf16)a3.x; o1[5] = (bf16)a3.y; o1[6] = (bf16)a3.z; o1[7] = (bf16)a3.w;
    *(bf16x8*)(dst + i) = o0;
    *(bf16x8*)(dst + i + 8) = o1;
  }
}

// ---------------- RMSNorm (optionally blended), fp32 in -> bf16 out ----------------
template<bool BLEND>
__global__ __launch_bounds__(256) void prenorm_k(const float* __restrict__ x, const float* __restrict__ x0,
                                                 const float* __restrict__ lambdas, bf16* __restrict__ out) {
  const int t = blockIdx.x, tid = threadIdx.x;
  const float4* xr = (const float4*)(x + (size_t)t * DD);
  float4 a0 = xr[2 * tid], a1 = xr[2 * tid + 1];
  float v[8] = {a0.x, a0.y, a0.z, a0.w, a1.x, a1.y, a1.z, a1.w};
  if (BLEND) {
    const float l0 = lambdas[0], l1 = lambdas[1];
    const float4* yr = (const float4*)(x0 + (size_t)t * DD);
    float4 b0 = yr[2 * tid], b1 = yr[2 * tid + 1];
    float w[8] = {b0.x, b0.y, b0.z, b0.w, b1.x, b1.y, b1.z, b1.w};
#pragma unroll
    for (int i = 0; i < 8; ++i) v[i] = l0 * v[i] + l1 * w[i];
  }
  float ss = 0.f;
#pragma unroll
  for (int i = 0; i < 8; ++i) ss += v[i] * v[i];
#pragma unroll
  for (int off = 1; off < 64; off <<= 1) ss += __shfl_xor(ss, off, 64);
  __shared__ float red[4];
  const int wid = tid >> 6;
  if ((tid & 63) == 0) red[wid] = ss;
  __syncthreads();
  ss = red[0] + red[1] + red[2] + red[3];
  const float sc = rsqrtf(ss * (1.0f / DD) + 1.1920928955078125e-07f);
  bf16x8 o;
#pragma unroll
  for (int i = 0; i < 8; ++i) o[i] = (bf16)(v[i] * sc);
  *(bf16x8*)(out + (size_t)t * DD + tid * 8) = o;
}

// ---------------- per-(t,h) RMSNorm + rotary, in-place on bf16 q/k ----------------
__global__ __launch_bounds__(256) void rope_k(bf16* __restrict__ qg, bf16* __restrict__ kg) {
  const int tid = threadIdx.x, lane = tid & 63, wid = tid >> 6;
  const int p = blockIdx.x * 4 + wid;          // [arr(2)][t(2048)][h(16)]
  bf16* base = ((p >> 15) ? kg : qg);
  const int t = (p >> 4) & 2047, hh = p & 15;
  base += (size_t)t * DD + hh * 128;
  float x1 = (float)base[lane], x2 = (float)base[lane + 64];
  float ss = x1 * x1 + x2 * x2;
#pragma unroll
  for (int off = 1; off < 64; off <<= 1) ss += __shfl_xor(ss, off, 64);
  const float sc = rsqrtf(ss * (1.0f / 128.0f) + 1.1920928955078125e-07f);
  x1 *= sc; x2 *= sc;
  const float fr = (float)t * exp2f((float)lane * (-13.287712379549449f / 64.0f));
  const float s = sinf(fr), c = cosf(fr);
  base[lane]      = (bf16)(x1 * c + x2 * s);
  base[lane + 64] = (bf16)(-x1 * s + x2 * c);
}

// ---------------- V transpose: v[t][2048] -> vt[d2][t] ----------------
__global__ __launch_bounds__(256) void vt_k(const bf16* __restrict__ v, bf16* __restrict__ vt) {
  __shared__ alignas(16) bf16 tile[16 * 128];
  const int tb = blockIdx.x, hb = blockIdx.y, tid = threadIdx.x;
  glds16(v + (size_t)(tb * 16 + (tid >> 4)) * DD + hb * 128 + (tid & 15) * 8, tile + tid * 8);
  __syncthreads();
  const int d_l = tid & 127, tc = tid >> 7;
  bf16x8 o;
#pragma unroll
  for (int i = 0; i < 8; ++i) o[i] = tile[(tc * 8 + i) * 128 + d_l];
  *(bf16x8*)(vt + (size_t)(hb * 128 + d_l) * DD + tb * 16 + tc * 8) = o;
}

// ================ 256x256-tile, 8-wave, phase-interleaved GEMM ================
// 8 waves (2M x 4N). Phase = [dsr(cur); stage->other; counted vmcnt; barrier; MFMA].
// Stage units in consumption order U0=Ah0, U2=Bh0, U3=Bh1, U1=Ah1; vmcnt(4) steady.
__device__ __forceinline__ void g9_stageA(const bf16* A, int Kstride, int row0, int k0,
                                          bf16* buf, int hm, int tid) {
#pragma unroll
  for (int i = 0; i < 2; ++i) {
    int e = tid + i * 512;                 // [0,1024): prl = e>>3, slot = e&7
    int prl = e >> 3, slot = e & 7;
    int wm = prl >> 6, r63 = prl & 63;
    glds16(A + (size_t)(row0 + wm * 128 + hm * 64 + r63) * Kstride + k0 + ((slot ^ (prl & 7)) * 8),
           buf + hm * 8192 + e * 8);
  }
}
__device__ __forceinline__ void g9_stageB(const bf16* B, int Kstride, int col0, int k0,
                                          bf16* buf, int hn, int tid) {
#pragma unroll
  for (int i = 0; i < 2; ++i) {
    int e = tid + i * 512;
    int pbl = e >> 3, slot = e & 7;
    int wn = pbl >> 5, q = pbl & 31;
    glds16(B + (size_t)(col0 + wn * 64 + hn * 32 + q) * Kstride + k0 + ((slot ^ (pbl & 7)) * 8),
           buf + 16384 + hn * 8192 + e * 8);
  }
}

__device__ __forceinline__ void gemm9_core(const bf16* __restrict__ A, const bf16* __restrict__ B,
                                           int Kstride, int Klen, int row0, int col0,
                                           bf16* smem, f32x4 (&acc)[8][4]) {
  const int tid = threadIdx.x, lane = tid & 63, wid = tid >> 6;
  const int wm = wid >> 2, wn = wid & 3;
  const int l15 = lane & 15, g = lane >> 4;
  const int sw = l15 & 7;
  const int NT = Klen >> 6;
  // prologue: tile 0 in consumption order U0,U2,U3,U1
  g9_stageA(A, Kstride, row0, 0, smem, 0, tid);
  g9_stageB(B, Kstride, col0, 0, smem, 0, tid);
  g9_stageB(B, Kstride, col0, 0, smem, 1, tid);
  g9_stageA(A, Kstride, row0, 0, smem, 1, tid);
  asm volatile("s_waitcnt vmcnt(4)" ::: "memory");
  __builtin_amdgcn_s_barrier();

  bf16x8 a[4][2], b0[2][2], b1[2][2];
  for (int t = 0; t < NT; ++t) {
    bf16* cb = smem + (t & 1) * 32768;
    bf16* sb = smem + ((t + 1) & 1) * 32768;
    const int ks0 = (t + 1) << 6;
    const bool st = (t + 1) < NT;
    // ---- PH1: dsr a(hm0), b0(hn0); stage U0'; wait U3; bar; MFMA Q(0,0)
#pragma unroll
    for (int mm = 0; mm < 4; ++mm)
#pragma unroll
      for (int ks = 0; ks < 2; ++ks)
        a[mm][ks] = *(const bf16x8*)(cb + (wm * 64 + mm * 16 + l15) * 64 + (((ks * 4 + g) ^ sw) * 8));
#pragma unroll
    for (int nn = 0; nn < 2; ++nn)
#pragma unroll
      for (int ks = 0; ks < 2; ++ks)
        b0[nn][ks] = *(const bf16x8*)(cb + 16384 + (wn * 32 + nn * 16 + l15) * 64 + (((ks * 4 + g) ^ sw) * 8));
    if (st) g9_stageA(A, Kstride, row0, ks0, sb, 0, tid);
    if (st) { asm volatile("s_waitcnt vmcnt(4)" ::: "memory"); }
    else    { asm volatile("s_waitcnt vmcnt(2)" ::: "memory"); }
    __builtin_amdgcn_s_barrier();
    __builtin_amdgcn_s_setprio(1);
#pragma unroll
    for (int mm = 0; mm < 4; ++mm)
#pragma unroll
      for (int nn = 0; nn < 2; ++nn)
#pragma unroll
        for (int ks = 0; ks < 2; ++ks)
          acc[mm][nn] = mfma16(a[mm][ks], b0[nn][ks], acc[mm][nn]);
    __builtin_amdgcn_s_setprio(0);
    // ---- PH2: dsr b1(hn1); stage U2'; wait U1; bar; MFMA Q(0,1)
#pragma unroll
    for (int nn = 0; nn < 2; ++nn)
#pragma unroll
      for (int ks = 0; ks < 2; ++ks)
        b1[nn][ks] = *(const bf16x8*)(cb + 16384 + 8192 + (wn * 32 + nn * 16 + l15) * 64 + (((ks * 4 + g) ^ sw) * 8));
    if (st) g9_stageB(B, Kstride, col0, ks0, sb, 0, tid);
    if (st) { asm volatile("s_waitcnt vmcnt(4)" ::: "memory"); }
    else    { asm volatile("s_waitcnt vmcnt(0)" ::: "memory"); }
    __builtin_amdgcn_s_barrier();
    __builtin_amdgcn_s_setprio(1);
#pragma unroll
    for (int mm = 0; mm < 4; ++mm)
#pragma unroll
      for (int nn = 0; nn < 2; ++nn)
#pragma unroll
        for (int ks = 0; ks < 2; ++ks)
          acc[mm][2 + nn] = mfma16(a[mm][ks], b1[nn][ks], acc[mm][2 + nn]);
    __builtin_amdgcn_s_setprio(0);
    // ---- PH3: dsr a(hm1); stage U3'; bar; MFMA Q(1,0)
#pragma unroll
    for (int mm = 0; mm < 4; ++mm)
#pragma unroll
      for (int ks = 0; ks < 2; ++ks)
        a[mm][ks] = *(const bf16x8*)(cb + 8192 + (wm * 64 + mm * 16 + l15) * 64 + (((ks * 4 + g) ^ sw) * 8));
    if (st) g9_stageB(B, Kstride, col0, ks0, sb, 1, tid);
    __builtin_amdgcn_s_barrier();
    __builtin_amdgcn_s_setprio(1);
#pragma unroll
    for (int mm = 0; mm < 4; ++mm)
#pragma unroll
      for (int nn = 0; nn < 2; ++nn)
#pragma unroll
        for (int ks = 0; ks < 2; ++ks)
          acc[4 + mm][nn] = mfma16(a[mm][ks], b0[nn][ks], acc[4 + mm][nn]);
    __builtin_amdgcn_s_setprio(0);
    // ---- PH4: stage U1'; wait U0',U2' (for next PH1 dsr); bar; MFMA Q(1,1)
    if (st) { g9_stageA(A, Kstride, row0, ks0, sb, 1, tid);
              asm volatile("s_waitcnt vmcnt(4)" ::: "memory"); }
    __builtin_amdgcn_s_barrier();
    __builtin_amdgcn_s_setprio(1);
#pragma unroll
    for (int mm = 0; mm < 4; ++mm)
#pragma unroll
      for (int nn = 0; nn < 2; ++nn)
#pragma unroll
        for (int ks = 0; ks < 2; ++ks)
          acc[4 + mm][2 + nn] = mfma16(a[mm][ks], b1[nn][ks], acc[4 + mm][2 + nn]);
    __builtin_amdgcn_s_setprio(0);
  }
}

// D layout: col=lane&15, row=(lane>>4)*4+j; acc[m][n]: hm=m>>2, mm=m&3, hn=n>>1, nn=n&1
#define GEMM9_EPI(STMT)                                                        \
  { const int lane_ = threadIdx.x & 63, wid_ = threadIdx.x >> 6;               \
    const int l15_ = lane_ & 15, g_ = lane_ >> 4;                              \
    const int wm_ = wid_ >> 2, wn_ = wid_ & 3;                                 \
    _Pragma("unroll") for (int m = 0; m < 8; ++m)                              \
    _Pragma("unroll") for (int n = 0; n < 4; ++n)                              \
    _Pragma("unroll") for (int j = 0; j < 4; ++j) {                            \
      int grow = row0 + wm_ * 128 + (m >> 2) * 64 + (m & 3) * 16 + g_ * 4 + j; \
      int gcol = col0 + wn_ * 64 + (n >> 1) * 32 + (n & 1) * 16 + l15_;        \
      float vacc = acc[m][n][j];                                               \
      STMT; } }

__global__ __launch_bounds__(512, 1) void gemm9_qkv(const bf16* __restrict__ A,
    const bf16* __restrict__ Wq, const bf16* __restrict__ Wk, const bf16* __restrict__ Wv,
    bf16* __restrict__ oq, bf16* __restrict__ ok, bf16* __restrict__ ov,
    const float* __restrict__ vi, const float* __restrict__ lambp) {
  extern __shared__ bf16 smem9[];
  const int z = blockIdx.z;
  const bf16* B = (z == 0) ? Wq : (z == 1) ? Wk : Wv;
  bf16* out = (z == 0) ? oq : (z == 1) ? ok : ov;
  const int row0 = blockIdx.y * 256, col0 = blockIdx.x * 256;
  f32x4 acc[8][4] = {};
  gemm9_core(A, B, DD, DD, row0, col0, smem9, acc);
  if (z < 2) {
    GEMM9_EPI( out[(size_t)grow * DD + gcol] = (bf16)vacc; )
  } else {
    const float lam = *lambp;
    GEMM9_EPI( out[(size_t)grow * DD + gcol] =
                 (bf16)((1.0f - lam) * vacc + lam * vi[(size_t)grow * DD + gcol]); )
  }
}

// split-K partial GEMM: z < zsw -> o1 + z*DD2 ; else o2 + (z-zsw)*DD2
__global__ __launch_bounds__(512, 1) void gemm9_part(const bf16* __restrict__ A, const bf16* __restrict__ B,
                                                     float* __restrict__ o1, float* __restrict__ o2,
                                                     int zsw, int N, int Kstride, int Klen) {
  extern __shared__ bf16 smem9[];
  const int row0 = blockIdx.y * 256, col0 = blockIdx.x * 256;
  const int z = blockIdx.z, kofs = z * Klen;
  float* out = (z < zsw) ? (o1 + (size_t)z * DD2) : (o2 + (size_t)(z - zsw) * DD2);
  f32x4 acc[8][4] = {};
  gemm9_core(A + kofs, B + kofs, Kstride, Klen, row0, col0, smem9, acc);
  GEMM9_EPI( out[(size_t)grow * N + gcol] = vacc; )
}

__global__ __launch_bounds__(512, 1) void gemm9_relu(const bf16* __restrict__ A, const bf16* __restrict__ B,
                                                     bf16* __restrict__ out, int N, int Kstride, int Klen) {
  extern __shared__ bf16 smem9[];
  const int row0 = blockIdx.y * 256, col0 = blockIdx.x * 256;
  f32x4 acc[8][4] = {};
  gemm9_core(A, B, Kstride, Klen, row0, col0, smem9, acc);
  GEMM9_EPI( float r = fmaxf(vacc, 0.f); out[(size_t)grow * N + gcol] = (bf16)(r * r); )
}

// ---------------- split-K reduces ----------------
__global__ __launch_bounds__(256) void wo_red_prenorm(const float* __restrict__ pa, const float* __restrict__ pb,
                                                      float* __restrict__ a_f, bf16* __restrict__ an) {
  const int t = blockIdx.x, tid = threadIdx.x;
  const size_t base = (size_t)t * DD + tid * 8;
  float v[8];
#pragma unroll
  for (int h = 0; h < 2; ++h) {
    size_t i = base + h * 4;
    float4 r0 = *(const float4*)(pa + i);
    float4 r1 = *(const float4*)(pa + DD2 + i);
    float4 r2 = *(const float4*)(pb + i);
    float4 r3 = *(const float4*)(pb + DD2 + i);
    v[h*4+0] = r0.x + r1.x + r2.x + r3.x;
    v[h*4+1] = r0.y + r1.y + r2.y + r3.y;
    v[h*4+2] = r0.z + r1.z + r2.z + r3.z;
    v[h*4+3] = r0.w + r1.w + r2.w + r3.w;
  }
  *(float4*)(a_f + base)     = make_float4(v[0], v[1], v[2], v[3]);
  *(float4*)(a_f + base + 4) = make_float4(v[4], v[5], v[6], v[7]);
  float ss = 0.f;
#pragma unroll
  for (int i = 0; i < 8; ++i) ss += v[i] * v[i];
#pragma unroll
  for (int off = 1; off < 64; off <<= 1) ss += __shfl_xor(ss, off, 64);
  __shared__ float red[4];
  if ((tid & 63) == 0) red[tid >> 6] = ss;
  __syncthreads();
  ss = red[0] + red[1] + red[2] + red[3];
  const float sc = rsqrtf(ss * (1.0f / DD) + 1.1920928955078125e-07f);
  bf16x8 o;
#pragma unroll
  for (int i = 0; i < 8; ++i) o[i] = (bf16)(v[i] * sc);
  *(bf16x8*)(an + base) = o;
}

__global__ __launch_bounds__(256) void proj_red(const float* __restrict__ pa, const float* __restrict__ pw,
                                                const float* __restrict__ a_f, float* __restrict__ out) {
  const size_t base = ((size_t)blockIdx.x * 256 + threadIdx.x) * 8;
#pragma unroll
  for (int h = 0; h < 2; ++h) {
    size_t i = base + h * 4;
    float4 r = *(const float4*)(a_f + i);
    float4 u = *(const float4*)(pa + i);
    float4 w = *(const float4*)(pa + DD2 + i);
    float4 z = *(const float4*)(pa + 2 * DD2 + i);
    float4 y = *(const float4*)(pw + i);
    *(float4*)(out + i) = make_float4(r.x + u.x + w.x + z.x + y.x,
                                      r.y + u.y + w.y + z.y + y.y,
                                      r.z + u.z + w.z + z.z + y.z,
                                      r.w + u.w + w.w + z.w + y.w);
  }
}

// ---------------- causal flash attention ----------------
// Swapped QK^T (lane holds S[q=l15][k]), no-max softmax (q,k RMS-normed: |s|<=11.32),
// P->A-frag via cvt-pack + 8 shfl (no LDS round trip), triple-buffered K/V staging
// with one barrier + counted vmcnt per tile.
__device__ __forceinline__ void att_stageK(const bf16* kg, int h, int kt, bf16* dst, int tid) {
#pragma unroll
  for (int r = 0; r < 2; ++r) {
    int e = tid + r * 256, row = e >> 4, slot = e & 15;
    glds16(kg + (size_t)(kt * 32 + row) * DD + h * 128 + ((slot ^ (row & 7)) * 8), dst + e * 8);
  }
}
__device__ __forceinline__ void att_stageV(const bf16* vtg, int h, int kt, bf16* dst, int tid) {
#pragma unroll
  for (int r = 0; r < 2; ++r) {
    int e = tid + r * 256, d = e >> 2, slot = e & 3;
    glds16(vtg + (size_t)(h * 128 + d) * DD + kt * 32 + ((slot ^ ((d >> 1) & 3)) * 8), dst + e * 8);
  }
}

__global__ __launch_bounds__(256) void attn_k(const bf16* __restrict__ qg, const bf16* __restrict__ kg,
                                              const bf16* __restrict__ vtg, bf16* __restrict__ yg) {
  __shared__ alignas(16) bf16 Ks[3][32 * 128];
  __shared__ alignas(16) bf16 Vt[3][128 * 32];
  const int h = blockIdx.y, qb = 31 - blockIdx.x;
  const int tid = threadIdx.x, lane = tid & 63, wid = tid >> 6;
  const int l15 = lane & 15, g = lane >> 4, swl = l15 & 7;
  const int qrow = qb * 64 + wid * 16;
  const float scale = 0.08838834764831845f;   // 1/sqrt(128)
  bf16x8 aQ[4];
  {
    const bf16* qp = qg + (size_t)(qrow + l15) * DD + h * 128 + g * 8;
#pragma unroll
    for (int kc = 0; kc < 4; ++kc) aQ[kc] = *(const bf16x8*)(qp + kc * 32);
  }
  f32x4 acc[8] = {};
  float lsum = 0.f;
  const int nkt = qb * 2 + 2;                 // always >= 2
  att_stageK(kg, h, 0, Ks[0], tid);
  att_stageV(vtg, h, 0, Vt[0], tid);
  att_stageK(kg, h, 1, Ks[1], tid);
  att_stageV(vtg, h, 1, Vt[1], tid);
  asm volatile("s_waitcnt vmcnt(4)" ::: "memory");   // tile0 (+Q) landed
  __builtin_amdgcn_s_barrier();
  int cur = 0;
  for (int kt = 0; kt < nkt; ++kt) {
    const int kbase = kt * 32;
    const int nb = (cur >= 1) ? cur - 1 : 2;  // (cur+2)%3
    // K fragments (A-operand: lane row = k)
    bf16x8 kf0[4], kf1[4];
#pragma unroll
    for (int kc = 0; kc < 4; ++kc) {
      kf0[kc] = *(const bf16x8*)(Ks[cur] + l15 * 128 + (((kc * 4 + g) ^ swl) * 8));
      kf1[kc] = *(const bf16x8*)(Ks[cur] + (16 + l15) * 128 + (((kc * 4 + g) ^ swl) * 8));
    }
    if (kt + 2 < nkt) { att_stageK(kg, h, kt + 2, Ks[nb], tid);
                        att_stageV(vtg, h, kt + 2, Vt[nb], tid); }
    // S^T = K * Q^T : lane holds S[q=l15][k=kbase+4g+j (+16)]
    f32x4 S0 = {}, S1 = {};
#pragma unroll
    for (int kc = 0; kc < 4; ++kc) {
      S0 = mfma16(kf0[kc], aQ[kc], S0);
      S1 = mfma16(kf1[kc], aQ[kc], S1);
    }
    const int q = qrow + l15;
    float p0[4], p1[4];
#pragma unroll
    for (int j = 0; j < 4; ++j) {
      int k0 = kbase + 4 * g + j;
      p0[j] = (k0 <= q) ? __expf(S0[j] * scale) : 0.f;
      p1[j] = (k0 + 16 <= q) ? __expf(S1[j] * scale) : 0.f;
      lsum += p0[j] + p1[j];
    }
    // pack to bf16 pairs, redistribute to PV A-frag layout (lane needs k = 8g..8g+7 for q=l15)
    unsigned w0 = pk2(p0[0], p0[1]), w1 = pk2(p0[2], p0[3]);
    unsigned w2 = pk2(p1[0], p1[1]), w3 = pk2(p1[2], p1[3]);
    const int s0l = (g & 1) * 32 + l15, s1l = s0l + 16;
    const bool hi = g >= 2;
    unsigned t00 = __shfl(w0, s0l, 64), t10 = __shfl(w1, s0l, 64);
    unsigned t01 = __shfl(w0, s1l, 64), t11 = __shfl(w1, s1l, 64);
    unsigned u00 = __shfl(w2, s0l, 64), u10 = __shfl(w3, s0l, 64);
    unsigned u01 = __shfl(w2, s1l, 64), u11 = __shfl(w3, s1l, 64);
    u32x4 av = { hi ? u00 : t00, hi ? u10 : t10, hi ? u01 : t01, hi ? u11 : t11 };
    bf16x8 aP = __builtin_bit_cast(bf16x8, av);
#pragma unroll
    for (int dt = 0; dt < 8; ++dt) {
      int d = dt * 16 + l15;
      bf16x8 bV = *(const bf16x8*)(Vt[cur] + d * 32 + ((g ^ ((d >> 1) & 3)) * 8));
      acc[dt] = mfma16(aP, bV, acc[dt]);
    }
    if (kt + 1 < nkt) {
      if (kt + 2 < nkt) { asm volatile("s_waitcnt vmcnt(4)" ::: "memory"); }
      else              { asm volatile("s_waitcnt vmcnt(0)" ::: "memory"); }
      __builtin_amdgcn_s_barrier();
    }
    cur = (cur == 2) ? 0 : cur + 1;
  }
  lsum += __shfl_xor(lsum, 16, 64);
  lsum += __shfl_xor(lsum, 32, 64);
  f32x4 linv;
#pragma unroll
  for (int j = 0; j < 4; ++j) linv[j] = 1.0f / __shfl(lsum, 4 * g + j, 64);
#pragma unroll
  for (int dt = 0; dt < 8; ++dt)
#pragma unroll
    for (int j = 0; j < 4; ++j) {
      int q = qrow + 4 * g + j;
      yg[(size_t)q * DD + h * 128 + dt * 16 + l15] = (bf16)(acc[dt][j] * linv[j]);
    }
}

extern "C" void kernel_launch(void* const* d_in, const int* in_sizes, int n_in,
                              void* d_out, int out_size, void* d_ws, size_t ws_size,
                              hipStream_t stream) {
  const float* x       = (const float*)d_in[0];
  const float* vi      = (const float*)d_in[1];
  const float* x0      = (const float*)d_in[2];
  const float* wq      = (const float*)d_in[3];
  const float* wk      = (const float*)d_in[4];
  const float* wv      = (const float*)d_in[5];
  const float* wo      = (const float*)d_in[6];
  const float* lamb    = (const float*)d_in[7];
  const float* lambdas = (const float*)d_in[8];
  const float* wfc     = (const float*)d_in[9];
  const float* wproj   = (const float*)d_in[10];
  float* out = (float*)d_out;

  (void)hipFuncSetAttribute(reinterpret_cast<const void*>(gemm9_qkv),
                            hipFuncAttributeMaxDynamicSharedMemorySize, G9_LDS);
  (void)hipFuncSetAttribute(reinterpret_cast<const void*>(gemm9_part),
                            hipFuncAttributeMaxDynamicSharedMemorySize, G9_LDS);
  (void)hipFuncSetAttribute(reinterpret_cast<const void*>(gemm9_relu),
                            hipFuncAttributeMaxDynamicSharedMemorySize, G9_LDS);

  char* wsb = (char*)d_ws;
  size_t off = 0;
  auto alloc = [&](size_t bytes) { void* p = wsb + off; off = (off + bytes + 255) & ~(size_t)255; return p; };
  bf16* wq_b  = (bf16*)alloc(DD2 * 2);
  bf16* wk_b  = (bf16*)alloc(DD2 * 2);
  bf16* wv_b  = (bf16*)alloc(DD2 * 2);
  bf16* wo_b  = (bf16*)alloc(DD2 * 2);
  bf16* wfc_b = (bf16*)alloc(DD2 * 8);   // dead after fc -> proj 4th partial
  bf16* wpj_b = (bf16*)alloc(DD2 * 8);
  // xn..an: 48MB contiguous; doubles as split-K f32 partials when dead
  bf16* xn_b  = (bf16*)alloc(DD2 * 2);
  bf16* q_b   = (bf16*)alloc(DD2 * 2);
  bf16* k_b   = (bf16*)alloc(DD2 * 2);
  bf16* v_b   = (bf16*)alloc(DD2 * 2);
  bf16* y_b   = (bf16*)alloc(DD2 * 2);
  bf16* an_b  = (bf16*)alloc(DD2 * 2);
  float* partA = (float*)xn_b;           // wo: splits 0,1 (xn..v) ; proj: splits 0..2 (xn..an)
  float* a_f  = (float*)alloc(DD2 * 4);
  bf16* h_b   = (bf16*)alloc(DD2 * 8);
  bf16* vt_b  = h_b;                     // vt dead before wo partials / fc output reuse h_b
  float* partB = (float*)h_b;            // wo: splits 2,3

  // weights for the attention half (wq..wo): grid-stride convert
  cvt_seg<<<2048, 256, 0, stream>>>(wq, wk, wv, wo, (bf16*)wsb, 22, 4 * DD2);
  prenorm_k<true><<<2048, 256, 0, stream>>>(x, x0, lambdas, xn_b);
  gemm9_qkv<<<dim3(8, 8, 3), 512, G9_LDS, stream>>>(xn_b, wq_b, wk_b, wv_b, q_b, k_b, v_b, vi, lamb);
  rope_k<<<16384, 256, 0, stream>>>(q_b, k_b);
  vt_k<<<dim3(128, 16), 256, 0, stream>>>(v_b, vt_b);
  attn_k<<<dim3(32, 16), 256, 0, stream>>>(q_b, k_b, vt_b, y_b);
  gemm9_part<<<dim3(8, 8, 4), 512, G9_LDS, stream>>>(y_b, wo_b, partA, partB, 2, DD, DD, 512);
  wo_red_prenorm<<<2048, 256, 0, stream>>>(partA, partB, a_f, an_b);
  // MLP weights converted here so wfc_b/wpj_b are L3-hot for fc/proj
  cvt_seg<<<2048, 256, 0, stream>>>(wfc, wproj, wfc, wfc, wfc_b, 24, 8 * DD2);
  gemm9_relu<<<dim3(32, 8), 512, G9_LDS, stream>>>(an_b, wfc_b, h_b, 4 * DD, DD, DD);
  gemm9_part<<<dim3(8, 8, 4), 512, G9_LDS, stream>>>(h_b, wpj_b, partA, (float*)wfc_b, 3, DD, 4 * DD, 2048);
  proj_red<<<2048, 256, 0, stream>>>(partA, (float*)wfc_b, a_f, out);
}